// Round 20
// baseline (3605.827 us; speedup 1.0000x reference)
//
#include <hip/hip_runtime.h>
#include <cstddef>
#include <cstdint>

static constexpr int B  = 256;
static constexpr int T  = 64;
static constexpr int D  = 512;
static constexpr int HE = 1024;
static constexpr int L  = 512;

typedef unsigned short ushort_t;
typedef __attribute__((ext_vector_type(8))) short short8;
typedef __attribute__((ext_vector_type(8))) unsigned short ushort8_t;
typedef __attribute__((ext_vector_type(8))) _Float16 f16x8;
typedef __attribute__((ext_vector_type(4))) float f32x4;
typedef __attribute__((ext_vector_type(4))) unsigned short ushort4_t;

static constexpr float LO_SCALE   = 2048.0f;
static constexpr float LO_UNSCALE = 4.8828125e-4f;   // 1/2048

__device__ __forceinline__ float sigmoidf_(float x) { return 1.0f / (1.0f + expf(-x)); }

struct hfp { ushort_t hi, lo; };
__device__ __forceinline__ hfp f16_split(float v) {
    _Float16 h = (_Float16)v;
    _Float16 l = (_Float16)((v - (float)h) * LO_SCALE);
    hfp r;
    r.hi = __builtin_bit_cast(ushort_t, h);
    r.lo = __builtin_bit_cast(ushort_t, l);
    return r;
}

// Fragment-major tile layout: 16 rows x 32 k per 512-elem tile.
__device__ __forceinline__ size_t tile_off(int m, int n, int ldt) {
    return ((size_t)(m >> 4) * ldt + (n >> 5)) * 512
         + (size_t)((((m & 15) + (((n >> 3) & 3) << 4)) << 3) + (n & 7));
}

// ======================= weight/bias packing (output-major, coalesced writes) ==========
struct PkSeg { const float* src; ushort_t* hi; ushort_t* lo; int K, H, base; };  // base in chunks
struct PkAll { PkSeg s[16]; int total; };

__global__ void pack_all(PkAll pa)
{
    int idx = blockIdx.x * 256 + threadIdx.x;
    if (idx >= pa.total) return;
    int si = 0;
#pragma unroll
    for (int i = 1; i < 16; ++i) if (idx >= pa.s[i].base) si = i;
    const PkSeg sg = pa.s[si];
    int c = idx - sg.base;
    int ldt = sg.K >> 5;
    int t = c >> 6;
    int lane = c & 63;
    int m15 = lane & 15;
    int kg  = lane >> 4;
    int p  = (t / ldt) * 16 + m15;
    int k0 = (t % ldt) * 32 + kg * 8;
    int srow = p;
    if (sg.H) srow = ((p >> 4) & 3) * sg.H + (p >> 6) * 16 + (p & 15);
    const float* s = sg.src + (size_t)srow * sg.K + k0;
    ushort8_t h, l;
#pragma unroll
    for (int j = 0; j < 8; ++j) {
        hfp a = f16_split(s[j]);
        h[j] = a.hi; l[j] = a.lo;
    }
    size_t off = (size_t)t * 512 + lane * 8;
    *(ushort8_t*)(sg.hi + off) = h;
    *(ushort8_t*)(sg.lo + off) = l;
}

struct PbSeg { const float* b1; const float* b2; float* dst; int H, base; };
struct PbAll { PbSeg s[6]; int total; };

__global__ void pack_bias_all(PbAll pb)
{
    int idx = blockIdx.x * 256 + threadIdx.x;
    if (idx >= pb.total) return;
    int si = 0;
#pragma unroll
    for (int i = 1; i < 6; ++i) if (idx >= pb.s[i].base) si = i;
    const PbSeg sg = pb.s[si];
    int p = idx - sg.base;
    int srow = ((p >> 4) & 3) * sg.H + (p >> 6) * 16 + (p & 15);
    sg.dst[p] = sg.b1[srow] + sg.b2[srow];
}

// x [B][T][D] fp32 -> per-t tiled f16 pair planes; output-major (coalesced writes).
__global__ void conv_x(const float* __restrict__ x, ushort_t* __restrict__ xh,
                       ushort_t* __restrict__ xl)
{
    int idx = blockIdx.x * 256 + threadIdx.x;
    if (idx >= T * B * D / 8) return;
    int slab = idx >> 14;
    int c2 = idx & 16383;
    int t2 = c2 >> 6;
    int lane = c2 & 63;
    int tr = t2 >> 4, tc = t2 & 15;
    int b  = tr * 16 + (lane & 15);
    int k0 = tc * 32 + (lane >> 4) * 8;
    const float* s = x + ((size_t)b * T + slab) * D + k0;
    ushort8_t h, l;
#pragma unroll
    for (int j = 0; j < 8; ++j) {
        hfp a = f16_split(s[j]);
        h[j] = a.hi; l[j] = a.lo;
    }
    size_t off = (size_t)slab * B * D + (size_t)t2 * 512 + lane * 8;
    *(ushort8_t*)(xh + off) = h;
    *(ushort8_t*)(xl + off) = l;
}

// ======================= fp16x3 MFMA GEMM (tiled operands) =======================
struct Op {
    const ushort_t *Ahi, *Alo; int ldtA, kt0A;
    const ushort_t *Whi, *Wlo; int ldtW, kt0W;
    int K;
};
struct MArgs {
    Op op[3];
    const float* ci0; int ld0;
    int mode;                        // 0 plain, 1 lstm, 2 plain + prob-permute rows
    const float* cin; int cinLd;
    float* cout; int coutLd;
    ushort_t *hHi, *hLo; int hLdT;
    float* out; int outLd;
    ushort_t *pHi, *pLo; int pLdT;
};

__device__ __forceinline__ f32x4 MFH(short8 a, short8 w, f32x4 c) {
    return __builtin_amdgcn_mfma_f32_16x16x32_f16(
        __builtin_bit_cast(f16x8, a), __builtin_bit_cast(f16x8, w), c, 0, 0, 0);
}

// ---------------- split-K GEMM, two geometries ----------------
// WIDE=0: 32 rows x 64 cols; 4 waves split K 4-ways (proven R12 config).
// WIDE=1: 64 rows x 64 cols; 4 waves = 2 m-pair groups x 2 k-halves.
//   Wave w: m-tiles (w&1)*2+{0,1}, k-range half (w>>1). Same per-wave regs as
//   WIDE=0; y-blocks halve => weight stream from L2/HBM halves.
// Grid flattened 1-D; XCD swizzle keeps 8 consecutive bids on one x-column set.
template<int TAG, int WIDE>
__global__ __launch_bounds__(256) void gemm_sk(MArgs ga0, MArgs ga1)
{
    __shared__ float LV[4][2][4][4][64];   // [wave][mf][j][r][lane] = 32 KB
    const MArgs& ga = blockIdx.z ? ga1 : ga0;
    const int tid  = threadIdx.x;
    const int lane = tid & 63;
    const int wk   = tid >> 6;
    const int bid = blockIdx.x;
    int bx, by, m_w;
    if (WIDE) {
        bx = ((bid >> 5) << 3) | (bid & 7);
        by = (bid >> 3) & 3;
        m_w = by * 64;
    } else {
        bx = ((bid >> 6) << 3) | (bid & 7);
        by = (bid >> 3) & 7;
        m_w = by * 32;
    }
    const int n_w = bx * 64;
    const int l15 = lane & 15;
    const int mbase = (m_w >> 4) + (WIDE ? (wk & 1) * 2 : 0);

    f32x4 accH[2][4], accL[2][4];
#pragma unroll
    for (int mf = 0; mf < 2; ++mf)
#pragma unroll
        for (int j = 0; j < 4; ++j)
#pragma unroll
            for (int r = 0; r < 4; ++r) { accH[mf][j][r] = 0.0f; accL[mf][j][r] = 0.0f; }

    int NT = 0;
#pragma unroll
    for (int opi = 0; opi < 3; ++opi)
        if (ga.op[opi].Ahi && ga.op[opi].K > 0) NT += ga.op[opi].K >> 5;
    const int share = WIDE ? (NT >> 1) : (NT >> 2);
    int skip = (WIDE ? (wk >> 1) : wk) * share, cnt = share;

#pragma unroll 1
    for (int opi = 0; opi < 3 && cnt > 0; ++opi) {
        const Op o = ga.op[opi];
        if (o.Ahi == nullptr || o.K <= 0) continue;
        const int NK = o.K >> 5;
        if (skip >= NK) { skip -= NK; continue; }
        const int k0 = skip;
        const int k1 = (NK - k0 < cnt) ? NK : k0 + cnt;
        cnt -= (k1 - k0);
        skip = 0;

        const ushort_t *aHp[2], *aLp[2], *wHp[4], *wLp[4];
#pragma unroll
        for (int mf = 0; mf < 2; ++mf) {
            size_t ro = ((size_t)(mbase + mf) * o.ldtA + o.kt0A) * 512 + lane * 8;
            aHp[mf] = o.Ahi + ro; aLp[mf] = o.Alo + ro;
        }
#pragma unroll
        for (int j = 0; j < 4; ++j) {
            size_t ro = ((size_t)((n_w >> 4) + j) * o.ldtW + o.kt0W) * 512 + lane * 8;
            wHp[j] = o.Whi + ro; wLp[j] = o.Wlo + ro;
        }

        short8 A0[2], L0[2], W0[4], V0[4];
        short8 A1[2], L1[2], W1[4], V1[4];
        auto LD0 = [&](int ks) {
#pragma unroll
            for (int mf = 0; mf < 2; ++mf) {
                A0[mf] = *(const short8*)(aHp[mf] + (size_t)ks * 512);
                L0[mf] = *(const short8*)(aLp[mf] + (size_t)ks * 512);
            }
#pragma unroll
            for (int j = 0; j < 4; ++j) {
                W0[j] = *(const short8*)(wHp[j] + (size_t)ks * 512);
                V0[j] = *(const short8*)(wLp[j] + (size_t)ks * 512);
            }
        };
        auto LD1 = [&](int ks) {
#pragma unroll
            for (int mf = 0; mf < 2; ++mf) {
                A1[mf] = *(const short8*)(aHp[mf] + (size_t)ks * 512);
                L1[mf] = *(const short8*)(aLp[mf] + (size_t)ks * 512);
            }
#pragma unroll
            for (int j = 0; j < 4; ++j) {
                W1[j] = *(const short8*)(wHp[j] + (size_t)ks * 512);
                V1[j] = *(const short8*)(wLp[j] + (size_t)ks * 512);
            }
        };
        auto MM0 = [&]() {
#pragma unroll
            for (int mf = 0; mf < 2; ++mf)
#pragma unroll
                for (int j = 0; j < 4; ++j) {
                    accL[mf][j] = MFH(A0[mf], V0[j], accL[mf][j]);
                    accL[mf][j] = MFH(L0[mf], W0[j], accL[mf][j]);
                    accH[mf][j] = MFH(A0[mf], W0[j], accH[mf][j]);
                }
        };
        auto MM1 = [&]() {
#pragma unroll
            for (int mf = 0; mf < 2; ++mf)
#pragma unroll
                for (int j = 0; j < 4; ++j) {
                    accL[mf][j] = MFH(A1[mf], V1[j], accL[mf][j]);
                    accL[mf][j] = MFH(L1[mf], W1[j], accL[mf][j]);
                    accH[mf][j] = MFH(A1[mf], W1[j], accH[mf][j]);
                }
        };

        LD0(k0);
        int ks = k0;
        for (; ks + 2 < k1; ks += 2) {
            LD1(ks + 1);
            MM0();
            LD0(ks + 2);
            MM1();
        }
        if (ks + 1 < k1) { LD1(ks + 1); MM0(); MM1(); }
        else MM0();
    }

    // ---- fold lo into hi, store partials ----
#pragma unroll
    for (int mf = 0; mf < 2; ++mf)
#pragma unroll
        for (int j = 0; j < 4; ++j)
#pragma unroll
            for (int r = 0; r < 4; ++r)
                LV[wk][mf][j][r][lane] = accH[mf][j][r] + LO_UNSCALE * accL[mf][j][r];
    __syncthreads();

    if (WIDE) {
        // ---- reduce: wave wk handles local m-tile lt = wk; partials from
        //      waves {lt>>1, (lt>>1)+2} at mf = lt&1; r = 0..3 ----
        const int lt = wk;
        const int wb = lt >> 1;
        const int mfl = lt & 1;
#pragma unroll
        for (int r = 0; r < 4; ++r) {
            float g[4];
#pragma unroll
            for (int j = 0; j < 4; ++j) {
                float s = LV[wb][mfl][j][r][lane] + LV[wb + 2][mfl][j][r][lane];
                if (ga.ci0) s += ga.ci0[n_w + j * 16 + l15];
                g[j] = s;
            }
            const int m = m_w + lt * 16 + (lane >> 4) * 4 + r;
            if (ga.mode == 1) {
                const int n = (n_w >> 6) * 16 + l15;
                const float cold = ga.cin[(size_t)m * ga.cinLd + n];
                const float cn = sigmoidf_(g[1]) * cold + sigmoidf_(g[0]) * tanhf(g[2]);
                const float h  = sigmoidf_(g[3]) * tanhf(cn);
                ga.cout[(size_t)m * ga.coutLd + n] = cn;
                hfp hp = f16_split(h);
                size_t off = tile_off(m, n, ga.hLdT);
                ga.hHi[off] = hp.hi;
                ga.hLo[off] = hp.lo;
            } else {
#pragma unroll
                for (int j = 0; j < 4; ++j) {
                    const int p = n_w + j * 16 + l15;
                    int dst = m;
                    if (ga.mode == 2) dst = ((m & (B - 1)) << 6) + (m >> 8);
                    if (ga.out) ga.out[(size_t)dst * ga.outLd + p] = g[j];
                    if (ga.pHi) {
                        hfp vp = f16_split(g[j]);
                        size_t off = tile_off(m, p, ga.pLdT);
                        ga.pHi[off] = vp.hi;
                        ga.pLo[off] = vp.lo;
                    }
                }
            }
        }
    } else {
        // ---- reduce: wave wk handles mf = wk>>1, row-slots r = (wk&1)*2 + {0,1} ----
        const int mf = wk >> 1;
        const int rb = (wk & 1) * 2;
#pragma unroll
        for (int rr = 0; rr < 2; ++rr) {
            const int r = rb + rr;
            float g[4];
#pragma unroll
            for (int j = 0; j < 4; ++j) {
                float s = 0.0f;
#pragma unroll
                for (int w2 = 0; w2 < 4; ++w2) s += LV[w2][mf][j][r][lane];
                if (ga.ci0) s += ga.ci0[n_w + j * 16 + l15];
                g[j] = s;
            }
            const int m = m_w + mf * 16 + (lane >> 4) * 4 + r;
            if (ga.mode == 1) {
                const int n = (n_w >> 6) * 16 + l15;
                const float cold = ga.cin[(size_t)m * ga.cinLd + n];
                const float cn = sigmoidf_(g[1]) * cold + sigmoidf_(g[0]) * tanhf(g[2]);
                const float h  = sigmoidf_(g[3]) * tanhf(cn);
                ga.cout[(size_t)m * ga.coutLd + n] = cn;
                hfp hp = f16_split(h);
                size_t off = tile_off(m, n, ga.hLdT);
                ga.hHi[off] = hp.hi;
                ga.hLo[off] = hp.lo;
            } else {
#pragma unroll
                for (int j = 0; j < 4; ++j) {
                    const int p = n_w + j * 16 + l15;
                    int dst = m;
                    if (ga.mode == 2) dst = ((m & (B - 1)) << 6) + (m >> 8);
                    if (ga.out) ga.out[(size_t)dst * ga.outLd + p] = g[j];
                    if (ga.pHi) {
                        hfp vp = f16_split(g[j]);
                        size_t off = tile_off(m, p, ga.pLdT);
                        ga.pHi[off] = vp.hi;
                        ga.pLo[off] = vp.lo;
                    }
                }
            }
        }
    }
}

// ---------------- register-path GEMM (latent / feat / logits) ----------------
template<int TAG, int MF, int WM, int WN>
__global__ __launch_bounds__(WM * WN * 64) void gemm_t(MArgs ga0, MArgs ga1)
{
    const MArgs& ga = blockIdx.z ? ga1 : ga0;
    const int lane = threadIdx.x & 63;
    const int wid  = threadIdx.x >> 6;
    const int wy = wid / WN, wx = wid % WN;
    const int m_w = blockIdx.y * (WM * MF * 16) + wy * MF * 16;
    const int n_w = blockIdx.x * (WN * 64) + wx * 64;
    const int l15 = lane & 15;
    const int rB  = (lane >> 4) * 4;

    f32x4 accH[MF][4];
    f32x4 accL[MF][4];
#pragma unroll
    for (int mf = 0; mf < MF; ++mf)
#pragma unroll
        for (int j = 0; j < 4; ++j) {
            const int p = n_w + j * 16 + l15;
#pragma unroll
            for (int r = 0; r < 4; ++r) {
                float v = 0.0f;
                if (ga.ci0) v += ga.ci0[(size_t)(m_w + mf * 16 + rB + r) * ga.ld0 + p];
                accH[mf][j][r] = v;
                accL[mf][j][r] = 0.0f;
            }
        }

#pragma unroll 1
    for (int opi = 0; opi < 3; ++opi) {
        const Op o = ga.op[opi];
        if (o.Ahi == nullptr || o.K <= 0) continue;
        const ushort_t *aH[MF], *aL[MF], *wH[4], *wL[4];
#pragma unroll
        for (int mf = 0; mf < MF; ++mf) {
            size_t ro = ((size_t)((m_w >> 4) + mf) * o.ldtA + o.kt0A) * 512 + lane * 8;
            aH[mf] = o.Ahi + ro; aL[mf] = o.Alo + ro;
        }
#pragma unroll
        for (int j = 0; j < 4; ++j) {
            size_t ro = ((size_t)((n_w >> 4) + j) * o.ldtW + o.kt0W) * 512 + lane * 8;
            wH[j] = o.Whi + ro; wL[j] = o.Wlo + ro;
        }
        const int NK = o.K >> 5;

        auto LD = [&](short8* ah, short8* al, short8* wh, short8* wl, int ks) {
#pragma unroll
            for (int mf = 0; mf < MF; ++mf) {
                ah[mf] = *(const short8*)(aH[mf] + (size_t)ks * 512);
                al[mf] = *(const short8*)(aL[mf] + (size_t)ks * 512);
            }
#pragma unroll
            for (int j = 0; j < 4; ++j) {
                wh[j] = *(const short8*)(wH[j] + (size_t)ks * 512);
                wl[j] = *(const short8*)(wL[j] + (size_t)ks * 512);
            }
        };
        auto MM = [&](short8* ah, short8* al, short8* wh, short8* wl) {
#pragma unroll
            for (int mf = 0; mf < MF; ++mf)
#pragma unroll
                for (int j = 0; j < 4; ++j) {
                    accL[mf][j] = MFH(ah[mf], wl[j], accL[mf][j]);
                    accL[mf][j] = MFH(al[mf], wh[j], accL[mf][j]);
                    accH[mf][j] = MFH(ah[mf], wh[j], accH[mf][j]);
                }
        };

        short8 A0[MF], L0[MF], W0[4], V0[4];
        short8 A1[MF], L1[MF], W1[4], V1[4];
        LD(A0, L0, W0, V0, 0);
        int ks = 0;
        for (; ks + 2 < NK; ks += 2) {
            LD(A1, L1, W1, V1, ks + 1);
            MM(A0, L0, W0, V0);
            LD(A0, L0, W0, V0, ks + 2);
            MM(A1, L1, W1, V1);
        }
        LD(A1, L1, W1, V1, ks + 1);
        MM(A0, L0, W0, V0);
        MM(A1, L1, W1, V1);
    }

    if (ga.mode == 1) {
        const int n = (n_w >> 6) * 16 + l15;
#pragma unroll
        for (int mf = 0; mf < MF; ++mf)
#pragma unroll
            for (int r = 0; r < 4; ++r) {
                const int m = m_w + mf * 16 + rB + r;
                const float gi = accH[mf][0][r] + LO_UNSCALE * accL[mf][0][r];
                const float gf = accH[mf][1][r] + LO_UNSCALE * accL[mf][1][r];
                const float gg = accH[mf][2][r] + LO_UNSCALE * accL[mf][2][r];
                const float go = accH[mf][3][r] + LO_UNSCALE * accL[mf][3][r];
                const float cold = ga.cin[(size_t)m * ga.cinLd + n];
                const float cn = sigmoidf_(gf) * cold + sigmoidf_(gi) * tanhf(gg);
                const float h  = sigmoidf_(go) * tanhf(cn);
                ga.cout[(size_t)m * ga.coutLd + n] = cn;
                hfp hp = f16_split(h);
                size_t off = tile_off(m, n, ga.hLdT);
                ga.hHi[off] = hp.hi;
                ga.hLo[off] = hp.lo;
            }
    } else {
#pragma unroll
        for (int mf = 0; mf < MF; ++mf)
#pragma unroll
            for (int j = 0; j < 4; ++j) {
                const int p = n_w + j * 16 + l15;
#pragma unroll
                for (int r = 0; r < 4; ++r) {
                    const int m = m_w + mf * 16 + rB + r;
                    const float v = accH[mf][j][r] + LO_UNSCALE * accL[mf][j][r];
                    int dst = m;
                    if (ga.mode == 2) dst = ((m & (B - 1)) << 6) + (m >> 8);
                    if (ga.out) ga.out[(size_t)dst * ga.outLd + p] = v;
                    if (ga.pHi) {
                        hfp vp = f16_split(v);
                        size_t off = tile_off(m, p, ga.pLdT);
                        ga.pHi[off] = vp.hi;
                        ga.pLo[off] = vp.lo;
                    }
                }
            }
    }
}

// layernorm(mu), softplus(std), z = mu+eps*std -> c0,c1 (fp32) and z tiled f16 pairs
__global__ void latent2(float* __restrict__ mu, float* __restrict__ sd,
                        const float* __restrict__ eps, float* __restrict__ c0,
                        float* __restrict__ c1, ushort_t* __restrict__ zh,
                        ushort_t* __restrict__ zl)
{
    const int b = blockIdx.x, l = threadIdx.x;
    float* mrow = mu + (size_t)b * L;
    float4 v0 = *(const float4*)(mrow + l * 4);
    float4 v1 = *(const float4*)(mrow + 256 + l * 4);
    float s = v0.x + v0.y + v0.z + v0.w + v1.x + v1.y + v1.z + v1.w;
    float q = v0.x * v0.x + v0.y * v0.y + v0.z * v0.z + v0.w * v0.w
            + v1.x * v1.x + v1.y * v1.y + v1.z * v1.z + v1.w * v1.w;
#pragma unroll
    for (int off = 32; off; off >>= 1) { s += __shfl_xor(s, off); q += __shfl_xor(q, off); }
    const float mean = s * (1.0f / 512.0f);
    const float var  = q * (1.0f / 512.0f) - mean * mean;
    const float inv  = rsqrtf(var + 1e-5f);
    v0.x = (v0.x - mean) * inv; v0.y = (v0.y - mean) * inv; v0.z = (v0.z - mean) * inv; v0.w = (v0.w - mean) * inv;
    v1.x = (v1.x - mean) * inv; v1.y = (v1.y - mean) * inv; v1.z = (v1.z - mean) * inv; v1.w = (v1.w - mean) * inv;
    *(float4*)(mrow + l * 4) = v0;
    *(float4*)(mrow + 256 + l * 4) = v1;

    float* srow = sd + (size_t)b * L;
    float4 s0 = *(const float4*)(srow + l * 4);
    float4 s1 = *(const float4*)(srow + 256 + l * 4);
    s0.x = fmaxf(s0.x, 0.0f) + log1pf(expf(-fabsf(s0.x)));
    s0.y = fmaxf(s0.y, 0.0f) + log1pf(expf(-fabsf(s0.y)));
    s0.z = fmaxf(s0.z, 0.0f) + log1pf(expf(-fabsf(s0.z)));
    s0.w = fmaxf(s0.w, 0.0f) + log1pf(expf(-fabsf(s0.w)));
    s1.x = fmaxf(s1.x, 0.0f) + log1pf(expf(-fabsf(s1.x)));
    s1.y = fmaxf(s1.y, 0.0f) + log1pf(expf(-fabsf(s1.y)));
    s1.z = fmaxf(s1.z, 0.0f) + log1pf(expf(-fabsf(s1.z)));
    s1.w = fmaxf(s1.w, 0.0f) + log1pf(expf(-fabsf(s1.w)));
    *(float4*)(srow + l * 4) = s0;
    *(float4*)(srow + 256 + l * 4) = s1;

    const float* erow = eps + (size_t)b * L;
    float4 e0 = *(const float4*)(erow + l * 4);
    float4 e1 = *(const float4*)(erow + 256 + l * 4);
    float4 z0, z1;
    z0.x = v0.x + e0.x * s0.x; z0.y = v0.y + e0.y * s0.y; z0.z = v0.z + e0.z * s0.z; z0.w = v0.w + e0.w * s0.w;
    z1.x = v1.x + e1.x * s1.x; z1.y = v1.y + e1.y * s1.y; z1.z = v1.z + e1.z * s1.z; z1.w = v1.w + e1.w * s1.w;
    *(float4*)(c0 + (size_t)b * L + l * 4) = z0;
    *(float4*)(c0 + (size_t)b * L + 256 + l * 4) = z1;
    *(float4*)(c1 + (size_t)b * L + l * 4) = z0;
    *(float4*)(c1 + (size_t)b * L + 256 + l * 4) = z1;
    ushort4_t h, lo;
    hfp a;
    a = f16_split(z0.x); h[0] = a.hi; lo[0] = a.lo;
    a = f16_split(z0.y); h[1] = a.hi; lo[1] = a.lo;
    a = f16_split(z0.z); h[2] = a.hi; lo[2] = a.lo;
    a = f16_split(z0.w); h[3] = a.hi; lo[3] = a.lo;
    size_t o0 = tile_off(b, l * 4, 16);
    *(ushort4_t*)(zh + o0) = h;
    *(ushort4_t*)(zl + o0) = lo;
    a = f16_split(z1.x); h[0] = a.hi; lo[0] = a.lo;
    a = f16_split(z1.y); h[1] = a.hi; lo[1] = a.lo;
    a = f16_split(z1.z); h[2] = a.hi; lo[2] = a.lo;
    a = f16_split(z1.w); h[3] = a.hi; lo[3] = a.lo;
    size_t o1 = tile_off(b, 256 + l * 4, 16);
    *(ushort4_t*)(zh + o1) = h;
    *(ushort4_t*)(zl + o1) = lo;
}

// in-place softmax + argmax over all B*T rows; one wave per row.
__global__ void softmax_all(float* __restrict__ prob, float* __restrict__ label)
{
    const int r = blockIdx.x, l = threadIdx.x;
    float* row = prob + (size_t)r * D;
    float4 x0 = *(const float4*)(row + l * 4);
    float4 x1 = *(const float4*)(row + 256 + l * 4);
    float m = x0.x; int mi = l * 4;
    { float v; int i;
      v = x0.y; i = l * 4 + 1;       if (v > m) { m = v; mi = i; }
      v = x0.z; i = l * 4 + 2;       if (v > m) { m = v; mi = i; }
      v = x0.w; i = l * 4 + 3;       if (v > m) { m = v; mi = i; }
      v = x1.x; i = 256 + l * 4;     if (v > m) { m = v; mi = i; }
      v = x1.y; i = 256 + l * 4 + 1; if (v > m) { m = v; mi = i; }
      v = x1.z; i = 256 + l * 4 + 2; if (v > m) { m = v; mi = i; }
      v = x1.w; i = 256 + l * 4 + 3; if (v > m) { m = v; mi = i; } }
#pragma unroll
    for (int off = 32; off; off >>= 1) {
        float om = __shfl_xor(m, off);
        int   oi = __shfl_xor(mi, off);
        if (om > m || (om == m && oi < mi)) { m = om; mi = oi; }
    }
    float4 e0, e1;
    e0.x = expf(x0.x - m); e0.y = expf(x0.y - m); e0.z = expf(x0.z - m); e0.w = expf(x0.w - m);
    e1.x = expf(x1.x - m); e1.y = expf(x1.y - m); e1.z = expf(x1.z - m); e1.w = expf(x1.w - m);
    float s = e0.x + e0.y + e0.z + e0.w + e1.x + e1.y + e1.z + e1.w;
#pragma unroll
    for (int off = 32; off; off >>= 1) s += __shfl_xor(s, off);
    const float inv = 1.0f / s;
    e0.x *= inv; e0.y *= inv; e0.z *= inv; e0.w *= inv;
    e1.x *= inv; e1.y *= inv; e1.z *= inv; e1.w *= inv;
    *(float4*)(row + l * 4) = e0;
    *(float4*)(row + 256 + l * 4) = e1;
    if (l == 0) label[r] = (float)mi;
}

// ---------------------------------------------------------------------------
extern "C" void kernel_launch(void* const* d_in, const int* in_sizes, int n_in,
                              void* d_out, int out_size, void* d_ws, size_t ws_size,
                              hipStream_t stream)
{
    const float* x       = (const float*)d_in[0];
    const float* eps     = (const float*)d_in[1];
    const float* We_ih_f = (const float*)d_in[2];
    const float* We_hh_f = (const float*)d_in[3];
    const float* be_ih_f = (const float*)d_in[4];
    const float* be_hh_f = (const float*)d_in[5];
    const float* We_ih_b = (const float*)d_in[6];
    const float* We_hh_b = (const float*)d_in[7];
    const float* be_ih_b = (const float*)d_in[8];
    const float* be_hh_b = (const float*)d_in[9];
    const float* Wmu     = (const float*)d_in[10];
    const float* bmu     = (const float*)d_in[11];
    const float* Wstd    = (const float*)d_in[12];
    const float* bstd    = (const float*)d_in[13];
    const float* Wc_ih0  = (const float*)d_in[14];
    const float* Wc_hh0  = (const float*)d_in[15];
    const float* bc_ih0  = (const float*)d_in[16];
    const float* bc_hh0  = (const float*)d_in[17];
    const float* Wc_ih1  = (const float*)d_in[18];
    const float* Wc_hh1  = (const float*)d_in[19];
    const float* bc_ih1  = (const float*)d_in[20];
    const float* bc_hh1  = (const float*)d_in[21];
    const float* Wcl     = (const float*)d_in[22];
    const float* bcl     = (const float*)d_in[23];
    const float* Wd_ih0  = (const float*)d_in[24];
    const float* Wd_hh0  = (const float*)d_in[25];
    const float* bd_ih0  = (const float*)d_in[26];
    const float* bd_hh0  = (const float*)d_in[27];
    const float* Wd_ih1  = (const float*)d_in[28];
    const float* Wd_hh1  = (const float*)d_in[29];
    const float* bd_ih1  = (const float*)d_in[30];
    const float* bd_hh1  = (const float*)d_in[31];
    const float* Wlog    = (const float*)d_in[32];
    const float* blog    = (const float*)d_in[33];
    (void)in_sizes; (void)n_in; (void)out_size;

    float* out      = (float*)d_out;
    float* prob_out = out;
    float* mu_out   = out + (size_t)B * T * D;
    float* std_out  = mu_out + (size_t)B * L;
    float* lab_out  = std_out + (size_t)B * L;

    // ---------------- workspace layout ----------------
    char* cur = (char*)d_ws;
    auto alignup = [&]() { cur = (char*)(((uintptr_t)cur + 255) & ~(uintptr_t)255); };
    auto aU = [&](size_t elems) { alignup(); ushort_t* p = (ushort_t*)cur; cur += elems * 2; return p; };
    auto aF = [&](size_t elems) { alignup(); float* p = (float*)cur; cur += elems * 4; return p; };

    ushort_t* WefIh = aU((size_t)4*HE*D);  ushort_t* WefIl = aU((size_t)4*HE*D);
    ushort_t* WefHh = aU((size_t)4*HE*HE); ushort_t* WefHl = aU((size_t)4*HE*HE);
    ushort_t* WebIh = aU((size_t)4*HE*D);  ushort_t* WebIl = aU((size_t)4*HE*D);
    ushort_t* WebHh = aU((size_t)4*HE*HE); ushort_t* WebHl = aU((size_t)4*HE*HE);
    ushort_t* Wc0Ih = aU((size_t)4*L*L);   ushort_t* Wc0Il = aU((size_t)4*L*L);
    ushort_t* Wc0Hh = aU((size_t)4*L*L);   ushort_t* Wc0Hl = aU((size_t)4*L*L);
    ushort_t* Wc1Ih = aU((size_t)4*L*L);   ushort_t* Wc1Il = aU((size_t)4*L*L);
    ushort_t* Wc1Hh = aU((size_t)4*L*L);   ushort_t* Wc1Hl = aU((size_t)4*L*L);
    ushort_t* Wd0Ih = aU((size_t)4*L*(D+L)); ushort_t* Wd0Il = aU((size_t)4*L*(D+L));
    ushort_t* Wd0Hh = aU((size_t)4*L*L);   ushort_t* Wd0Hl = aU((size_t)4*L*L);
    ushort_t* Wd1Ih = aU((size_t)4*L*L);   ushort_t* Wd1Il = aU((size_t)4*L*L);
    ushort_t* Wd1Hh = aU((size_t)4*L*L);   ushort_t* Wd1Hl = aU((size_t)4*L*L);
    ushort_t* WmuH  = aU((size_t)L*2*HE);  ushort_t* WmuL  = aU((size_t)L*2*HE);
    ushort_t* WstdH = aU((size_t)L*2*HE);  ushort_t* WstdL = aU((size_t)L*2*HE);
    ushort_t* WclH  = aU((size_t)L*L);     ushort_t* WclL  = aU((size_t)L*L);
    ushort_t* WlogH = aU((size_t)D*L);     ushort_t* WlogL = aU((size_t)D*L);
    ushort_t* xh = aU((size_t)T*B*D);      ushort_t* xl = aU((size_t)T*B*D);
    ushort_t* hfh[2] = { aU((size_t)B*HE), aU((size_t)B*HE) };
    ushort_t* hfl[2] = { aU((size_t)B*HE), aU((size_t)B*HE) };
    ushort_t* hbh[2] = { aU((size_t)B*HE), aU((size_t)B*HE) };
    ushort_t* hbl[2] = { aU((size_t)B*HE), aU((size_t)B*HE) };
    ushort_t* zh = aU((size_t)B*L);        ushort_t* zl = aU((size_t)B*L);
    ushort_t* h0h[2] = { aU((size_t)B*L), aU((size_t)B*L) };
    ushort_t* h0l[2] = { aU((size_t)B*L), aU((size_t)B*L) };
    ushort_t* ftsH = aU((size_t)4*B*L);    ushort_t* ftsL = aU((size_t)4*B*L);
    ushort_t* featH = aU((size_t)4*B*L);   ushort_t* featL = aU((size_t)4*B*L);
    ushort_t* hd1h[2] = { aU((size_t)B*L), aU((size_t)B*L) };
    ushort_t* hd1l[2] = { aU((size_t)B*L), aU((size_t)B*L) };
    ushort_t* slabH = aU((size_t)T*B*L);   ushort_t* slabL = aU((size_t)T*B*L);
    float* cf   = aF((size_t)B*HE);
    float* cb   = aF((size_t)B*HE);
    float* zbuf = aF((size_t)B*HE);
    float* c0   = aF((size_t)B*L);
    float* c1   = aF((size_t)B*L);
    float* cd1  = aF((size_t)B*L);
    float* cd2  = aF((size_t)B*L);
    float* featF = aF((size_t)4*B*L);
    float* bEF = aF((size_t)4*HE);
    float* bEB = aF((size_t)4*HE);
    float* bC0 = aF((size_t)4*L);
    float* bC1 = aF((size_t)4*L);
    float* bD0 = aF((size_t)4*L);
    float* bD1 = aF((size_t)4*L);
    const size_t need = (size_t)(cur - (char*)d_ws);
    if (need > ws_size) return;

    // ==================== packing (single dispatch, output-major) ====================
    {
        PkAll pa{};
        int base = 0, i = 0;
        auto add = [&](const float* s, ushort_t* h, ushort_t* l, int Np, int K, int H) {
            pa.s[i++] = { s, h, l, K, H, base };
            base += Np * (K >> 3);
        };
        add(We_ih_f, WefIh, WefIl, 4*HE, D, HE);
        add(We_hh_f, WefHh, WefHl, 4*HE, HE, HE);
        add(We_ih_b, WebIh, WebIl, 4*HE, D, HE);
        add(We_hh_b, WebHh, WebHl, 4*HE, HE, HE);
        add(Wc_ih0, Wc0Ih, Wc0Il, 4*L, L, L);
        add(Wc_hh0, Wc0Hh, Wc0Hl, 4*L, L, L);
        add(Wc_ih1, Wc1Ih, Wc1Il, 4*L, L, L);
        add(Wc_hh1, Wc1Hh, Wc1Hl, 4*L, L, L);
        add(Wd_ih0, Wd0Ih, Wd0Il, 4*L, D+L, L);
        add(Wd_hh0, Wd0Hh, Wd0Hl, 4*L, L, L);
        add(Wd_ih1, Wd1Ih, Wd1Il, 4*L, L, L);
        add(Wd_hh1, Wd1Hh, Wd1Hl, 4*L, L, L);
        add(Wmu,  WmuH,  WmuL,  L, 2*HE, 0);
        add(Wstd, WstdH, WstdL, L, 2*HE, 0);
        add(Wcl,  WclH,  WclL,  L, L, 0);
        add(Wlog, WlogH, WlogL, D, L, 0);
        pa.total = base;
        pack_all<<<(pa.total + 255) / 256, 256, 0, stream>>>(pa);

        PbAll pb{};
        int bb = 0, k = 0;
        auto addb = [&](const float* b1, const float* b2, float* dst, int H) {
            pb.s[k++] = { b1, b2, dst, H, bb };
            bb += 4 * H;
        };
        addb(be_ih_f, be_hh_f, bEF, HE);
        addb(be_ih_b, be_hh_b, bEB, HE);
        addb(bc_ih0, bc_hh0, bC0, L);
        addb(bc_ih1, bc_hh1, bC1, L);
        addb(bd_ih0, bd_hh0, bD0, L);
        addb(bd_ih1, bd_hh1, bD1, L);
        pb.total = bb;
        pack_bias_all<<<(pb.total + 255) / 256, 256, 0, stream>>>(pb);
    }
    conv_x<<<(T*B*D/8 + 255) / 256, 256, 0, stream>>>(x, xh, xl);
    (void)hipMemsetAsync(zbuf, 0, (size_t)B * HE * sizeof(float), stream);

    // ---------- encoder (WIDE split-K: 64-row blocks, halved weight stream) ----------
    for (int t = 0; t < T; ++t) {
        MArgs f{};
        f.op[0] = { xh + (size_t)t*B*D, xl + (size_t)t*B*D, 16, 0, WefIh, WefIl, 16, 0, D };
        if (t) f.op[1] = { hfh[t&1], hfl[t&1], 32, 0, WefHh, WefHl, 32, 0, HE };
        f.ci0 = bEF; f.ld0 = 0;
        f.mode = 1;
        f.cin = t ? cf : zbuf; f.cinLd = HE;
        f.cout = cf; f.coutLd = HE;
        f.hHi = hfh[(t+1)&1]; f.hLo = hfl[(t+1)&1]; f.hLdT = 32;
        MArgs b = f;
        b.op[0] = { xh + (size_t)(T-1-t)*B*D, xl + (size_t)(T-1-t)*B*D, 16, 0, WebIh, WebIl, 16, 0, D };
        if (t) b.op[1] = { hbh[t&1], hbl[t&1], 32, 0, WebHh, WebHl, 32, 0, HE };
        b.ci0 = bEB;
        b.cin = t ? cb : zbuf;
        b.cout = cb;
        b.hHi = hbh[(t+1)&1]; b.hLo = hbl[(t+1)&1];
        gemm_sk<0,1><<<dim3((4*HE/64) * (B/64), 1, 2), 256, 0, stream>>>(f, b);
    }

    // ---------- latent ----------
    {
        MArgs m{};
        m.op[0] = { hfh[0], hfl[0], 32, 0, WmuH, WmuL, 64, 0, HE };
        m.op[1] = { hbh[0], hbl[0], 32, 0, WmuH, WmuL, 64, 32, HE };
        m.ci0 = bmu; m.ld0 = 0; m.mode = 0; m.out = mu_out; m.outLd = L;
        MArgs s = m;
        s.op[0].Whi = WstdH; s.op[0].Wlo = WstdL;
        s.op[1].Whi = WstdH; s.op[1].Wlo = WstdL;
        s.ci0 = bstd; s.out = std_out;
        gemm_t<3,1,1,1><<<dim3(L/64, B/16, 2), 64, 0, stream>>>(m, s);
        latent2<<<B, 64, 0, stream>>>(mu_out, std_out, eps, c0, c1, zh, zl);
    }

    // ---------- conductor (WIDE split-K, z-paired) ----------
    auto condL1 = [&](int bar) {
        MArgs a{};
        a.op[0] = { zh, zl, 16, 0, Wc0Ih, Wc0Il, 16, 0, L };
        a.op[1] = { bar ? h0h[(bar-1)&1] : zh, bar ? h0l[(bar-1)&1] : zl, 16, 0, Wc0Hh, Wc0Hl, 16, 0, L };
        a.ci0 = bC0; a.ld0 = 0; a.mode = 1;
        a.cin = c0; a.cinLd = L; a.cout = c0; a.coutLd = L;
        a.hHi = h0h[bar&1]; a.hLo = h0l[bar&1]; a.hLdT = 16;
        return a;
    };
    auto condL2 = [&](int bar) {
        MArgs a2{};
        a2.op[0] = { h0h[bar&1], h0l[bar&1], 16, 0, Wc1Ih, Wc1Il, 16, 0, L };
        if (bar) a2.op[1] = { ftsH + (size_t)(bar-1)*B*L, ftsL + (size_t)(bar-1)*B*L, 16, 0, Wc1Hh, Wc1Hl, 16, 0, L };
        else     a2.op[1] = { zh, zl, 16, 0, Wc1Hh, Wc1Hl, 16, 0, L };
        a2.ci0 = bC1; a2.ld0 = 0; a2.mode = 1;
        a2.cin = c1; a2.cinLd = L; a2.cout = c1; a2.coutLd = L;
        a2.hHi = ftsH + (size_t)bar*B*L; a2.hLo = ftsL + (size_t)bar*B*L; a2.hLdT = 16;
        return a2;
    };
    {
        MArgs l1 = condL1(0);
        gemm_sk<2,1><<<dim3((4*L/64) * (B/64), 1, 1), 256, 0, stream>>>(l1, l1);
        for (int bar = 0; bar < 4; ++bar) {
            MArgs l2 = condL2(bar);
            if (bar + 1 < 4) {
                MArgs n1 = condL1(bar + 1);
                gemm_sk<2,1><<<dim3((4*L/64) * (B/64), 1, 2), 256, 0, stream>>>(l2, n1);
            } else {
                gemm_sk<2,1><<<dim3((4*L/64) * (B/64), 1, 1), 256, 0, stream>>>(l2, l2);
            }
        }
    }
    {   // feat: M = 4B rows (bar-major), K = L
        MArgs af{};
        af.op[0] = { ftsH, ftsL, 16, 0, WclH, WclL, 16, 0, L };
        af.ci0 = bcl; af.ld0 = 0; af.mode = 0;
        af.out = featF; af.outLd = L;
        af.pHi = featH; af.pLo = featL; af.pLdT = 16;
        gemm_t<3,1,1,1><<<dim3(L/64, 4*B/16, 1), 64, 0, stream>>>(af, af);
    }

    // ---------- decoder (WIDE split-K, z-paired g2(t) + g1(t+1)) ----------
    auto decG1 = [&](int t) {
        const int bar = t >> 4;
        const bool rs = (t & 15) == 0;
        MArgs g1{};
        if (t) g1.op[0] = { xh + (size_t)(t-1)*B*D, xl + (size_t)(t-1)*B*D, 16, 0, Wd0Ih, Wd0Il, 32, 0, D };
        g1.op[1] = { featH + (size_t)bar*B*L, featL + (size_t)bar*B*L, 16, 0, Wd0Ih, Wd0Il, 32, 16, L };
        if (rs) g1.op[2] = { featH + (size_t)bar*B*L, featL + (size_t)bar*B*L, 16, 0, Wd0Hh, Wd0Hl, 16, 0, L };
        else    g1.op[2] = { hd1h[(t-1)&1], hd1l[(t-1)&1], 16, 0, Wd0Hh, Wd0Hl, 16, 0, L };
        g1.ci0 = bD0; g1.ld0 = 0; g1.mode = 1;
        g1.cin = rs ? featF + (size_t)bar*B*L : cd1; g1.cinLd = L;
        g1.cout = cd1; g1.coutLd = L;
        g1.hHi = hd1h[t&1]; g1.hLo = hd1l[t&1]; g1.hLdT = 16;
        return g1;
    };
    auto decG2 = [&](int t) {
        const int bar = t >> 4;
        const bool rs = (t & 15) == 0;
        MArgs g2{};
        g2.op[0] = { hd1h[t&1], hd1l[t&1], 16, 0, Wd1Ih, Wd1Il, 16, 0, L };
        if (rs) g2.op[1] = { featH + (size_t)bar*B*L, featL + (size_t)bar*B*L, 16, 0, Wd1Hh, Wd1Hl, 16, 0, L };
        else    g2.op[1] = { slabH + (size_t)(t-1)*B*L, slabL + (size_t)(t-1)*B*L, 16, 0, Wd1Hh, Wd1Hl, 16, 0, L };
        g2.ci0 = bD1; g2.ld0 = 0; g2.mode = 1;
        g2.cin = rs ? featF + (size_t)bar*B*L : cd2; g2.cinLd = L;
        g2.cout = cd2; g2.coutLd = L;
        g2.hHi = slabH + (size_t)t*B*L; g2.hLo = slabL + (size_t)t*B*L; g2.hLdT = 16;
        return g2;
    };
    {
        MArgs g1 = decG1(0);
        gemm_sk<4,1><<<dim3((4*L/64) * (B/64), 1, 1), 256, 0, stream>>>(g1, g1);
        for (int t = 0; t < T; ++t) {
            MArgs g2 = decG2(t);
            if (t + 1 < T) {
                MArgs n1 = decG1(t + 1);
                gemm_sk<4,1><<<dim3((4*L/64) * (B/64), 1, 2), 256, 0, stream>>>(g2, n1);
            } else {
                gemm_sk<4,1><<<dim3((4*L/64) * (B/64), 1, 1), 256, 0, stream>>>(g2, g2);
            }
        }
    }

    // ---------- logits (batched, 64x256 tile) + softmax ----------
    {
        MArgs lg{};
        lg.op[0] = { slabH, slabL, 16, 0, WlogH, WlogL, 16, 0, L };
        lg.ci0 = blog; lg.ld0 = 0; lg.mode = 2;
        lg.out = prob_out; lg.outLd = D;
        gemm_t<5,2,2,4><<<dim3(D/256, T*B/64, 1), 512, 0, stream>>>(lg, lg);
    }
    softmax_all<<<B * T, 64, 0, stream>>>(prob_out, lab_out);
}

// Round 21
// 3304.160 us; speedup vs baseline: 1.0913x; 1.0913x over previous
//
#include <hip/hip_runtime.h>
#include <cstddef>
#include <cstdint>

static constexpr int B  = 256;
static constexpr int T  = 64;
static constexpr int D  = 512;
static constexpr int HE = 1024;
static constexpr int L  = 512;

typedef unsigned short ushort_t;
typedef __attribute__((ext_vector_type(8))) short short8;
typedef __attribute__((ext_vector_type(8))) unsigned short ushort8_t;
typedef __attribute__((ext_vector_type(8))) _Float16 f16x8;
typedef __attribute__((ext_vector_type(4))) float f32x4;
typedef __attribute__((ext_vector_type(4))) unsigned short ushort4_t;

static constexpr float LO_SCALE   = 2048.0f;
static constexpr float LO_UNSCALE = 4.8828125e-4f;   // 1/2048

__device__ __forceinline__ float sigmoidf_(float x) { return 1.0f / (1.0f + expf(-x)); }

struct hfp { ushort_t hi, lo; };
__device__ __forceinline__ hfp f16_split(float v) {
    _Float16 h = (_Float16)v;
    _Float16 l = (_Float16)((v - (float)h) * LO_SCALE);
    hfp r;
    r.hi = __builtin_bit_cast(ushort_t, h);
    r.lo = __builtin_bit_cast(ushort_t, l);
    return r;
}

// Fragment-major tile layout: 16 rows x 32 k per 512-elem tile.
__device__ __forceinline__ size_t tile_off(int m, int n, int ldt) {
    return ((size_t)(m >> 4) * ldt + (n >> 5)) * 512
         + (size_t)((((m & 15) + (((n >> 3) & 3) << 4)) << 3) + (n & 7));
}

// ======================= weight/bias packing (output-major, coalesced writes) ==========
struct PkSeg { const float* src; ushort_t* hi; ushort_t* lo; int K, H, base; };  // base in chunks
struct PkAll { PkSeg s[16]; int total; };

__global__ void pack_all(PkAll pa)
{
    int idx = blockIdx.x * 256 + threadIdx.x;
    if (idx >= pa.total) return;
    int si = 0;
#pragma unroll
    for (int i = 1; i < 16; ++i) if (idx >= pa.s[i].base) si = i;
    const PkSeg sg = pa.s[si];
    int c = idx - sg.base;
    int ldt = sg.K >> 5;
    int t = c >> 6;
    int lane = c & 63;
    int m15 = lane & 15;
    int kg  = lane >> 4;
    int p  = (t / ldt) * 16 + m15;
    int k0 = (t % ldt) * 32 + kg * 8;
    int srow = p;
    if (sg.H) srow = ((p >> 4) & 3) * sg.H + (p >> 6) * 16 + (p & 15);
    const float* s = sg.src + (size_t)srow * sg.K + k0;
    ushort8_t h, l;
#pragma unroll
    for (int j = 0; j < 8; ++j) {
        hfp a = f16_split(s[j]);
        h[j] = a.hi; l[j] = a.lo;
    }
    size_t off = (size_t)t * 512 + lane * 8;
    *(ushort8_t*)(sg.hi + off) = h;
    *(ushort8_t*)(sg.lo + off) = l;
}

struct PbSeg { const float* b1; const float* b2; float* dst; int H, base; };
struct PbAll { PbSeg s[6]; int total; };

__global__ void pack_bias_all(PbAll pb)
{
    int idx = blockIdx.x * 256 + threadIdx.x;
    if (idx >= pb.total) return;
    int si = 0;
#pragma unroll
    for (int i = 1; i < 6; ++i) if (idx >= pb.s[i].base) si = i;
    const PbSeg sg = pb.s[si];
    int p = idx - sg.base;
    int srow = ((p >> 4) & 3) * sg.H + (p >> 6) * 16 + (p & 15);
    sg.dst[p] = sg.b1[srow] + sg.b2[srow];
}

// x [B][T][D] fp32 -> per-t tiled f16 pair planes; output-major (coalesced writes).
__global__ void conv_x(const float* __restrict__ x, ushort_t* __restrict__ xh,
                       ushort_t* __restrict__ xl)
{
    int idx = blockIdx.x * 256 + threadIdx.x;
    if (idx >= T * B * D / 8) return;
    int slab = idx >> 14;
    int c2 = idx & 16383;
    int t2 = c2 >> 6;
    int lane = c2 & 63;
    int tr = t2 >> 4, tc = t2 & 15;
    int b  = tr * 16 + (lane & 15);
    int k0 = tc * 32 + (lane >> 4) * 8;
    const float* s = x + ((size_t)b * T + slab) * D + k0;
    ushort8_t h, l;
#pragma unroll
    for (int j = 0; j < 8; ++j) {
        hfp a = f16_split(s[j]);
        h[j] = a.hi; l[j] = a.lo;
    }
    size_t off = (size_t)slab * B * D + (size_t)t2 * 512 + lane * 8;
    *(ushort8_t*)(xh + off) = h;
    *(ushort8_t*)(xl + off) = l;
}

// ======================= fp16x3 MFMA GEMM (tiled operands) =======================
struct Op {
    const ushort_t *Ahi, *Alo; int ldtA, kt0A;
    const ushort_t *Whi, *Wlo; int ldtW, kt0W;
    int K;
};
struct MArgs {
    Op op[3];
    const float* ci0; int ld0;
    int mode;                        // 0 plain, 1 lstm, 2 plain + prob-permute rows
    const float* cin; int cinLd;
    float* cout; int coutLd;
    ushort_t *hHi, *hLo; int hLdT;
    float* out; int outLd;
    ushort_t *pHi, *pLo; int pLdT;
};

__device__ __forceinline__ f32x4 MFH(short8 a, short8 w, f32x4 c) {
    return __builtin_amdgcn_mfma_f32_16x16x32_f16(
        __builtin_bit_cast(f16x8, a), __builtin_bit_cast(f16x8, w), c, 0, 0, 0);
}

// ---------------- split-K GEMM, two geometries ----------------
// WIDE=0: 32 rows x 64 cols; 4 waves split K 4-ways (proven R12 config).
//   Shortest per-wave serial K-path => use for latency-bound chain phases
//   (conductor/decoder; R20 falsified WIDE there: −290 us).
// WIDE=1: 64 rows x 64 cols; 4 waves = 2 m-pair groups x 2 k-halves.
//   Halves weight stream => use for BW-bound phases (encoder; R19: +210 us win).
// Grid flattened 1-D; XCD swizzle keeps 8 consecutive bids on one x-column set.
template<int TAG, int WIDE>
__global__ __launch_bounds__(256) void gemm_sk(MArgs ga0, MArgs ga1)
{
    __shared__ float LV[4][2][4][4][64];   // [wave][mf][j][r][lane] = 32 KB
    const MArgs& ga = blockIdx.z ? ga1 : ga0;
    const int tid  = threadIdx.x;
    const int lane = tid & 63;
    const int wk   = tid >> 6;
    const int bid = blockIdx.x;
    int bx, by, m_w;
    if (WIDE) {
        bx = ((bid >> 5) << 3) | (bid & 7);
        by = (bid >> 3) & 3;
        m_w = by * 64;
    } else {
        bx = ((bid >> 6) << 3) | (bid & 7);
        by = (bid >> 3) & 7;
        m_w = by * 32;
    }
    const int n_w = bx * 64;
    const int l15 = lane & 15;
    const int mbase = (m_w >> 4) + (WIDE ? (wk & 1) * 2 : 0);

    f32x4 accH[2][4], accL[2][4];
#pragma unroll
    for (int mf = 0; mf < 2; ++mf)
#pragma unroll
        for (int j = 0; j < 4; ++j)
#pragma unroll
            for (int r = 0; r < 4; ++r) { accH[mf][j][r] = 0.0f; accL[mf][j][r] = 0.0f; }

    int NT = 0;
#pragma unroll
    for (int opi = 0; opi < 3; ++opi)
        if (ga.op[opi].Ahi && ga.op[opi].K > 0) NT += ga.op[opi].K >> 5;
    const int share = WIDE ? (NT >> 1) : (NT >> 2);
    int skip = (WIDE ? (wk >> 1) : wk) * share, cnt = share;

#pragma unroll 1
    for (int opi = 0; opi < 3 && cnt > 0; ++opi) {
        const Op o = ga.op[opi];
        if (o.Ahi == nullptr || o.K <= 0) continue;
        const int NK = o.K >> 5;
        if (skip >= NK) { skip -= NK; continue; }
        const int k0 = skip;
        const int k1 = (NK - k0 < cnt) ? NK : k0 + cnt;
        cnt -= (k1 - k0);
        skip = 0;

        const ushort_t *aHp[2], *aLp[2], *wHp[4], *wLp[4];
#pragma unroll
        for (int mf = 0; mf < 2; ++mf) {
            size_t ro = ((size_t)(mbase + mf) * o.ldtA + o.kt0A) * 512 + lane * 8;
            aHp[mf] = o.Ahi + ro; aLp[mf] = o.Alo + ro;
        }
#pragma unroll
        for (int j = 0; j < 4; ++j) {
            size_t ro = ((size_t)((n_w >> 4) + j) * o.ldtW + o.kt0W) * 512 + lane * 8;
            wHp[j] = o.Whi + ro; wLp[j] = o.Wlo + ro;
        }

        short8 A0[2], L0[2], W0[4], V0[4];
        short8 A1[2], L1[2], W1[4], V1[4];
        auto LD0 = [&](int ks) {
#pragma unroll
            for (int mf = 0; mf < 2; ++mf) {
                A0[mf] = *(const short8*)(aHp[mf] + (size_t)ks * 512);
                L0[mf] = *(const short8*)(aLp[mf] + (size_t)ks * 512);
            }
#pragma unroll
            for (int j = 0; j < 4; ++j) {
                W0[j] = *(const short8*)(wHp[j] + (size_t)ks * 512);
                V0[j] = *(const short8*)(wLp[j] + (size_t)ks * 512);
            }
        };
        auto LD1 = [&](int ks) {
#pragma unroll
            for (int mf = 0; mf < 2; ++mf) {
                A1[mf] = *(const short8*)(aHp[mf] + (size_t)ks * 512);
                L1[mf] = *(const short8*)(aLp[mf] + (size_t)ks * 512);
            }
#pragma unroll
            for (int j = 0; j < 4; ++j) {
                W1[j] = *(const short8*)(wHp[j] + (size_t)ks * 512);
                V1[j] = *(const short8*)(wLp[j] + (size_t)ks * 512);
            }
        };
        auto MM0 = [&]() {
#pragma unroll
            for (int mf = 0; mf < 2; ++mf)
#pragma unroll
                for (int j = 0; j < 4; ++j) {
                    accL[mf][j] = MFH(A0[mf], V0[j], accL[mf][j]);
                    accL[mf][j] = MFH(L0[mf], W0[j], accL[mf][j]);
                    accH[mf][j] = MFH(A0[mf], W0[j], accH[mf][j]);
                }
        };
        auto MM1 = [&]() {
#pragma unroll
            for (int mf = 0; mf < 2; ++mf)
#pragma unroll
                for (int j = 0; j < 4; ++j) {
                    accL[mf][j] = MFH(A1[mf], V1[j], accL[mf][j]);
                    accL[mf][j] = MFH(L1[mf], W1[j], accL[mf][j]);
                    accH[mf][j] = MFH(A1[mf], W1[j], accH[mf][j]);
                }
        };

        LD0(k0);
        int ks = k0;
        for (; ks + 2 < k1; ks += 2) {
            LD1(ks + 1);
            MM0();
            LD0(ks + 2);
            MM1();
        }
        if (ks + 1 < k1) { LD1(ks + 1); MM0(); MM1(); }
        else MM0();
    }

    // ---- fold lo into hi, store partials ----
#pragma unroll
    for (int mf = 0; mf < 2; ++mf)
#pragma unroll
        for (int j = 0; j < 4; ++j)
#pragma unroll
            for (int r = 0; r < 4; ++r)
                LV[wk][mf][j][r][lane] = accH[mf][j][r] + LO_UNSCALE * accL[mf][j][r];
    __syncthreads();

    if (WIDE) {
        // ---- reduce: wave wk handles local m-tile lt = wk; partials from
        //      waves {lt>>1, (lt>>1)+2} at mf = lt&1; r = 0..3 ----
        const int lt = wk;
        const int wb = lt >> 1;
        const int mfl = lt & 1;
#pragma unroll
        for (int r = 0; r < 4; ++r) {
            float g[4];
#pragma unroll
            for (int j = 0; j < 4; ++j) {
                float s = LV[wb][mfl][j][r][lane] + LV[wb + 2][mfl][j][r][lane];
                if (ga.ci0) s += ga.ci0[n_w + j * 16 + l15];
                g[j] = s;
            }
            const int m = m_w + lt * 16 + (lane >> 4) * 4 + r;
            if (ga.mode == 1) {
                const int n = (n_w >> 6) * 16 + l15;
                const float cold = ga.cin[(size_t)m * ga.cinLd + n];
                const float cn = sigmoidf_(g[1]) * cold + sigmoidf_(g[0]) * tanhf(g[2]);
                const float h  = sigmoidf_(g[3]) * tanhf(cn);
                ga.cout[(size_t)m * ga.coutLd + n] = cn;
                hfp hp = f16_split(h);
                size_t off = tile_off(m, n, ga.hLdT);
                ga.hHi[off] = hp.hi;
                ga.hLo[off] = hp.lo;
            } else {
#pragma unroll
                for (int j = 0; j < 4; ++j) {
                    const int p = n_w + j * 16 + l15;
                    int dst = m;
                    if (ga.mode == 2) dst = ((m & (B - 1)) << 6) + (m >> 8);
                    if (ga.out) ga.out[(size_t)dst * ga.outLd + p] = g[j];
                    if (ga.pHi) {
                        hfp vp = f16_split(g[j]);
                        size_t off = tile_off(m, p, ga.pLdT);
                        ga.pHi[off] = vp.hi;
                        ga.pLo[off] = vp.lo;
                    }
                }
            }
        }
    } else {
        // ---- reduce: wave wk handles mf = wk>>1, row-slots r = (wk&1)*2 + {0,1} ----
        const int mf = wk >> 1;
        const int rb = (wk & 1) * 2;
#pragma unroll
        for (int rr = 0; rr < 2; ++rr) {
            const int r = rb + rr;
            float g[4];
#pragma unroll
            for (int j = 0; j < 4; ++j) {
                float s = 0.0f;
#pragma unroll
                for (int w2 = 0; w2 < 4; ++w2) s += LV[w2][mf][j][r][lane];
                if (ga.ci0) s += ga.ci0[n_w + j * 16 + l15];
                g[j] = s;
            }
            const int m = m_w + mf * 16 + (lane >> 4) * 4 + r;
            if (ga.mode == 1) {
                const int n = (n_w >> 6) * 16 + l15;
                const float cold = ga.cin[(size_t)m * ga.cinLd + n];
                const float cn = sigmoidf_(g[1]) * cold + sigmoidf_(g[0]) * tanhf(g[2]);
                const float h  = sigmoidf_(g[3]) * tanhf(cn);
                ga.cout[(size_t)m * ga.coutLd + n] = cn;
                hfp hp = f16_split(h);
                size_t off = tile_off(m, n, ga.hLdT);
                ga.hHi[off] = hp.hi;
                ga.hLo[off] = hp.lo;
            } else {
#pragma unroll
                for (int j = 0; j < 4; ++j) {
                    const int p = n_w + j * 16 + l15;
                    int dst = m;
                    if (ga.mode == 2) dst = ((m & (B - 1)) << 6) + (m >> 8);
                    if (ga.out) ga.out[(size_t)dst * ga.outLd + p] = g[j];
                    if (ga.pHi) {
                        hfp vp = f16_split(g[j]);
                        size_t off = tile_off(m, p, ga.pLdT);
                        ga.pHi[off] = vp.hi;
                        ga.pLo[off] = vp.lo;
                    }
                }
            }
        }
    }
}

// ---------------- register-path GEMM (latent / feat / logits) ----------------
template<int TAG, int MF, int WM, int WN>
__global__ __launch_bounds__(WM * WN * 64) void gemm_t(MArgs ga0, MArgs ga1)
{
    const MArgs& ga = blockIdx.z ? ga1 : ga0;
    const int lane = threadIdx.x & 63;
    const int wid  = threadIdx.x >> 6;
    const int wy = wid / WN, wx = wid % WN;
    const int m_w = blockIdx.y * (WM * MF * 16) + wy * MF * 16;
    const int n_w = blockIdx.x * (WN * 64) + wx * 64;
    const int l15 = lane & 15;
    const int rB  = (lane >> 4) * 4;

    f32x4 accH[MF][4];
    f32x4 accL[MF][4];
#pragma unroll
    for (int mf = 0; mf < MF; ++mf)
#pragma unroll
        for (int j = 0; j < 4; ++j) {
            const int p = n_w + j * 16 + l15;
#pragma unroll
            for (int r = 0; r < 4; ++r) {
                float v = 0.0f;
                if (ga.ci0) v += ga.ci0[(size_t)(m_w + mf * 16 + rB + r) * ga.ld0 + p];
                accH[mf][j][r] = v;
                accL[mf][j][r] = 0.0f;
            }
        }

#pragma unroll 1
    for (int opi = 0; opi < 3; ++opi) {
        const Op o = ga.op[opi];
        if (o.Ahi == nullptr || o.K <= 0) continue;
        const ushort_t *aH[MF], *aL[MF], *wH[4], *wL[4];
#pragma unroll
        for (int mf = 0; mf < MF; ++mf) {
            size_t ro = ((size_t)((m_w >> 4) + mf) * o.ldtA + o.kt0A) * 512 + lane * 8;
            aH[mf] = o.Ahi + ro; aL[mf] = o.Alo + ro;
        }
#pragma unroll
        for (int j = 0; j < 4; ++j) {
            size_t ro = ((size_t)((n_w >> 4) + j) * o.ldtW + o.kt0W) * 512 + lane * 8;
            wH[j] = o.Whi + ro; wL[j] = o.Wlo + ro;
        }
        const int NK = o.K >> 5;

        auto LD = [&](short8* ah, short8* al, short8* wh, short8* wl, int ks) {
#pragma unroll
            for (int mf = 0; mf < MF; ++mf) {
                ah[mf] = *(const short8*)(aH[mf] + (size_t)ks * 512);
                al[mf] = *(const short8*)(aL[mf] + (size_t)ks * 512);
            }
#pragma unroll
            for (int j = 0; j < 4; ++j) {
                wh[j] = *(const short8*)(wH[j] + (size_t)ks * 512);
                wl[j] = *(const short8*)(wL[j] + (size_t)ks * 512);
            }
        };
        auto MM = [&](short8* ah, short8* al, short8* wh, short8* wl) {
#pragma unroll
            for (int mf = 0; mf < MF; ++mf)
#pragma unroll
                for (int j = 0; j < 4; ++j) {
                    accL[mf][j] = MFH(ah[mf], wl[j], accL[mf][j]);
                    accL[mf][j] = MFH(al[mf], wh[j], accL[mf][j]);
                    accH[mf][j] = MFH(ah[mf], wh[j], accH[mf][j]);
                }
        };

        short8 A0[MF], L0[MF], W0[4], V0[4];
        short8 A1[MF], L1[MF], W1[4], V1[4];
        LD(A0, L0, W0, V0, 0);
        int ks = 0;
        for (; ks + 2 < NK; ks += 2) {
            LD(A1, L1, W1, V1, ks + 1);
            MM(A0, L0, W0, V0);
            LD(A0, L0, W0, V0, ks + 2);
            MM(A1, L1, W1, V1);
        }
        LD(A1, L1, W1, V1, ks + 1);
        MM(A0, L0, W0, V0);
        MM(A1, L1, W1, V1);
    }

    if (ga.mode == 1) {
        const int n = (n_w >> 6) * 16 + l15;
#pragma unroll
        for (int mf = 0; mf < MF; ++mf)
#pragma unroll
            for (int r = 0; r < 4; ++r) {
                const int m = m_w + mf * 16 + rB + r;
                const float gi = accH[mf][0][r] + LO_UNSCALE * accL[mf][0][r];
                const float gf = accH[mf][1][r] + LO_UNSCALE * accL[mf][1][r];
                const float gg = accH[mf][2][r] + LO_UNSCALE * accL[mf][2][r];
                const float go = accH[mf][3][r] + LO_UNSCALE * accL[mf][3][r];
                const float cold = ga.cin[(size_t)m * ga.cinLd + n];
                const float cn = sigmoidf_(gf) * cold + sigmoidf_(gi) * tanhf(gg);
                const float h  = sigmoidf_(go) * tanhf(cn);
                ga.cout[(size_t)m * ga.coutLd + n] = cn;
                hfp hp = f16_split(h);
                size_t off = tile_off(m, n, ga.hLdT);
                ga.hHi[off] = hp.hi;
                ga.hLo[off] = hp.lo;
            }
    } else {
#pragma unroll
        for (int mf = 0; mf < MF; ++mf)
#pragma unroll
            for (int j = 0; j < 4; ++j) {
                const int p = n_w + j * 16 + l15;
#pragma unroll
                for (int r = 0; r < 4; ++r) {
                    const int m = m_w + mf * 16 + rB + r;
                    const float v = accH[mf][j][r] + LO_UNSCALE * accL[mf][j][r];
                    int dst = m;
                    if (ga.mode == 2) dst = ((m & (B - 1)) << 6) + (m >> 8);
                    if (ga.out) ga.out[(size_t)dst * ga.outLd + p] = v;
                    if (ga.pHi) {
                        hfp vp = f16_split(v);
                        size_t off = tile_off(m, p, ga.pLdT);
                        ga.pHi[off] = vp.hi;
                        ga.pLo[off] = vp.lo;
                    }
                }
            }
    }
}

// layernorm(mu), softplus(std), z = mu+eps*std -> c0,c1 (fp32) and z tiled f16 pairs
__global__ void latent2(float* __restrict__ mu, float* __restrict__ sd,
                        const float* __restrict__ eps, float* __restrict__ c0,
                        float* __restrict__ c1, ushort_t* __restrict__ zh,
                        ushort_t* __restrict__ zl)
{
    const int b = blockIdx.x, l = threadIdx.x;
    float* mrow = mu + (size_t)b * L;
    float4 v0 = *(const float4*)(mrow + l * 4);
    float4 v1 = *(const float4*)(mrow + 256 + l * 4);
    float s = v0.x + v0.y + v0.z + v0.w + v1.x + v1.y + v1.z + v1.w;
    float q = v0.x * v0.x + v0.y * v0.y + v0.z * v0.z + v0.w * v0.w
            + v1.x * v1.x + v1.y * v1.y + v1.z * v1.z + v1.w * v1.w;
#pragma unroll
    for (int off = 32; off; off >>= 1) { s += __shfl_xor(s, off); q += __shfl_xor(q, off); }
    const float mean = s * (1.0f / 512.0f);
    const float var  = q * (1.0f / 512.0f) - mean * mean;
    const float inv  = rsqrtf(var + 1e-5f);
    v0.x = (v0.x - mean) * inv; v0.y = (v0.y - mean) * inv; v0.z = (v0.z - mean) * inv; v0.w = (v0.w - mean) * inv;
    v1.x = (v1.x - mean) * inv; v1.y = (v1.y - mean) * inv; v1.z = (v1.z - mean) * inv; v1.w = (v1.w - mean) * inv;
    *(float4*)(mrow + l * 4) = v0;
    *(float4*)(mrow + 256 + l * 4) = v1;

    float* srow = sd + (size_t)b * L;
    float4 s0 = *(const float4*)(srow + l * 4);
    float4 s1 = *(const float4*)(srow + 256 + l * 4);
    s0.x = fmaxf(s0.x, 0.0f) + log1pf(expf(-fabsf(s0.x)));
    s0.y = fmaxf(s0.y, 0.0f) + log1pf(expf(-fabsf(s0.y)));
    s0.z = fmaxf(s0.z, 0.0f) + log1pf(expf(-fabsf(s0.z)));
    s0.w = fmaxf(s0.w, 0.0f) + log1pf(expf(-fabsf(s0.w)));
    s1.x = fmaxf(s1.x, 0.0f) + log1pf(expf(-fabsf(s1.x)));
    s1.y = fmaxf(s1.y, 0.0f) + log1pf(expf(-fabsf(s1.y)));
    s1.z = fmaxf(s1.z, 0.0f) + log1pf(expf(-fabsf(s1.z)));
    s1.w = fmaxf(s1.w, 0.0f) + log1pf(expf(-fabsf(s1.w)));
    *(float4*)(srow + l * 4) = s0;
    *(float4*)(srow + 256 + l * 4) = s1;

    const float* erow = eps + (size_t)b * L;
    float4 e0 = *(const float4*)(erow + l * 4);
    float4 e1 = *(const float4*)(erow + 256 + l * 4);
    float4 z0, z1;
    z0.x = v0.x + e0.x * s0.x; z0.y = v0.y + e0.y * s0.y; z0.z = v0.z + e0.z * s0.z; z0.w = v0.w + e0.w * s0.w;
    z1.x = v1.x + e1.x * s1.x; z1.y = v1.y + e1.y * s1.y; z1.z = v1.z + e1.z * s1.z; z1.w = v1.w + e1.w * s1.w;
    *(float4*)(c0 + (size_t)b * L + l * 4) = z0;
    *(float4*)(c0 + (size_t)b * L + 256 + l * 4) = z1;
    *(float4*)(c1 + (size_t)b * L + l * 4) = z0;
    *(float4*)(c1 + (size_t)b * L + 256 + l * 4) = z1;
    ushort4_t h, lo;
    hfp a;
    a = f16_split(z0.x); h[0] = a.hi; lo[0] = a.lo;
    a = f16_split(z0.y); h[1] = a.hi; lo[1] = a.lo;
    a = f16_split(z0.z); h[2] = a.hi; lo[2] = a.lo;
    a = f16_split(z0.w); h[3] = a.hi; lo[3] = a.lo;
    size_t o0 = tile_off(b, l * 4, 16);
    *(ushort4_t*)(zh + o0) = h;
    *(ushort4_t*)(zl + o0) = lo;
    a = f16_split(z1.x); h[0] = a.hi; lo[0] = a.lo;
    a = f16_split(z1.y); h[1] = a.hi; lo[1] = a.lo;
    a = f16_split(z1.z); h[2] = a.hi; lo[2] = a.lo;
    a = f16_split(z1.w); h[3] = a.hi; lo[3] = a.lo;
    size_t o1 = tile_off(b, 256 + l * 4, 16);
    *(ushort4_t*)(zh + o1) = h;
    *(ushort4_t*)(zl + o1) = lo;
}

// in-place softmax + argmax over all B*T rows; one wave per row.
__global__ void softmax_all(float* __restrict__ prob, float* __restrict__ label)
{
    const int r = blockIdx.x, l = threadIdx.x;
    float* row = prob + (size_t)r * D;
    float4 x0 = *(const float4*)(row + l * 4);
    float4 x1 = *(const float4*)(row + 256 + l * 4);
    float m = x0.x; int mi = l * 4;
    { float v; int i;
      v = x0.y; i = l * 4 + 1;       if (v > m) { m = v; mi = i; }
      v = x0.z; i = l * 4 + 2;       if (v > m) { m = v; mi = i; }
      v = x0.w; i = l * 4 + 3;       if (v > m) { m = v; mi = i; }
      v = x1.x; i = 256 + l * 4;     if (v > m) { m = v; mi = i; }
      v = x1.y; i = 256 + l * 4 + 1; if (v > m) { m = v; mi = i; }
      v = x1.z; i = 256 + l * 4 + 2; if (v > m) { m = v; mi = i; }
      v = x1.w; i = 256 + l * 4 + 3; if (v > m) { m = v; mi = i; } }
#pragma unroll
    for (int off = 32; off; off >>= 1) {
        float om = __shfl_xor(m, off);
        int   oi = __shfl_xor(mi, off);
        if (om > m || (om == m && oi < mi)) { m = om; mi = oi; }
    }
    float4 e0, e1;
    e0.x = expf(x0.x - m); e0.y = expf(x0.y - m); e0.z = expf(x0.z - m); e0.w = expf(x0.w - m);
    e1.x = expf(x1.x - m); e1.y = expf(x1.y - m); e1.z = expf(x1.z - m); e1.w = expf(x1.w - m);
    float s = e0.x + e0.y + e0.z + e0.w + e1.x + e1.y + e1.z + e1.w;
#pragma unroll
    for (int off = 32; off; off >>= 1) s += __shfl_xor(s, off);
    const float inv = 1.0f / s;
    e0.x *= inv; e0.y *= inv; e0.z *= inv; e0.w *= inv;
    e1.x *= inv; e1.y *= inv; e1.z *= inv; e1.w *= inv;
    *(float4*)(row + l * 4) = e0;
    *(float4*)(row + 256 + l * 4) = e1;
    if (l == 0) label[r] = (float)mi;
}

// ---------------------------------------------------------------------------
extern "C" void kernel_launch(void* const* d_in, const int* in_sizes, int n_in,
                              void* d_out, int out_size, void* d_ws, size_t ws_size,
                              hipStream_t stream)
{
    const float* x       = (const float*)d_in[0];
    const float* eps     = (const float*)d_in[1];
    const float* We_ih_f = (const float*)d_in[2];
    const float* We_hh_f = (const float*)d_in[3];
    const float* be_ih_f = (const float*)d_in[4];
    const float* be_hh_f = (const float*)d_in[5];
    const float* We_ih_b = (const float*)d_in[6];
    const float* We_hh_b = (const float*)d_in[7];
    const float* be_ih_b = (const float*)d_in[8];
    const float* be_hh_b = (const float*)d_in[9];
    const float* Wmu     = (const float*)d_in[10];
    const float* bmu     = (const float*)d_in[11];
    const float* Wstd    = (const float*)d_in[12];
    const float* bstd    = (const float*)d_in[13];
    const float* Wc_ih0  = (const float*)d_in[14];
    const float* Wc_hh0  = (const float*)d_in[15];
    const float* bc_ih0  = (const float*)d_in[16];
    const float* bc_hh0  = (const float*)d_in[17];
    const float* Wc_ih1  = (const float*)d_in[18];
    const float* Wc_hh1  = (const float*)d_in[19];
    const float* bc_ih1  = (const float*)d_in[20];
    const float* bc_hh1  = (const float*)d_in[21];
    const float* Wcl     = (const float*)d_in[22];
    const float* bcl     = (const float*)d_in[23];
    const float* Wd_ih0  = (const float*)d_in[24];
    const float* Wd_hh0  = (const float*)d_in[25];
    const float* bd_ih0  = (const float*)d_in[26];
    const float* bd_hh0  = (const float*)d_in[27];
    const float* Wd_ih1  = (const float*)d_in[28];
    const float* Wd_hh1  = (const float*)d_in[29];
    const float* bd_ih1  = (const float*)d_in[30];
    const float* bd_hh1  = (const float*)d_in[31];
    const float* Wlog    = (const float*)d_in[32];
    const float* blog    = (const float*)d_in[33];
    (void)in_sizes; (void)n_in; (void)out_size;

    float* out      = (float*)d_out;
    float* prob_out = out;
    float* mu_out   = out + (size_t)B * T * D;
    float* std_out  = mu_out + (size_t)B * L;
    float* lab_out  = std_out + (size_t)B * L;

    // ---------------- workspace layout ----------------
    char* cur = (char*)d_ws;
    auto alignup = [&]() { cur = (char*)(((uintptr_t)cur + 255) & ~(uintptr_t)255); };
    auto aU = [&](size_t elems) { alignup(); ushort_t* p = (ushort_t*)cur; cur += elems * 2; return p; };
    auto aF = [&](size_t elems) { alignup(); float* p = (float*)cur; cur += elems * 4; return p; };

    ushort_t* WefIh = aU((size_t)4*HE*D);  ushort_t* WefIl = aU((size_t)4*HE*D);
    ushort_t* WefHh = aU((size_t)4*HE*HE); ushort_t* WefHl = aU((size_t)4*HE*HE);
    ushort_t* WebIh = aU((size_t)4*HE*D);  ushort_t* WebIl = aU((size_t)4*HE*D);
    ushort_t* WebHh = aU((size_t)4*HE*HE); ushort_t* WebHl = aU((size_t)4*HE*HE);
    ushort_t* Wc0Ih = aU((size_t)4*L*L);   ushort_t* Wc0Il = aU((size_t)4*L*L);
    ushort_t* Wc0Hh = aU((size_t)4*L*L);   ushort_t* Wc0Hl = aU((size_t)4*L*L);
    ushort_t* Wc1Ih = aU((size_t)4*L*L);   ushort_t* Wc1Il = aU((size_t)4*L*L);
    ushort_t* Wc1Hh = aU((size_t)4*L*L);   ushort_t* Wc1Hl = aU((size_t)4*L*L);
    ushort_t* Wd0Ih = aU((size_t)4*L*(D+L)); ushort_t* Wd0Il = aU((size_t)4*L*(D+L));
    ushort_t* Wd0Hh = aU((size_t)4*L*L);   ushort_t* Wd0Hl = aU((size_t)4*L*L);
    ushort_t* Wd1Ih = aU((size_t)4*L*L);   ushort_t* Wd1Il = aU((size_t)4*L*L);
    ushort_t* Wd1Hh = aU((size_t)4*L*L);   ushort_t* Wd1Hl = aU((size_t)4*L*L);
    ushort_t* WmuH  = aU((size_t)L*2*HE);  ushort_t* WmuL  = aU((size_t)L*2*HE);
    ushort_t* WstdH = aU((size_t)L*2*HE);  ushort_t* WstdL = aU((size_t)L*2*HE);
    ushort_t* WclH  = aU((size_t)L*L);     ushort_t* WclL  = aU((size_t)L*L);
    ushort_t* WlogH = aU((size_t)D*L);     ushort_t* WlogL = aU((size_t)D*L);
    ushort_t* xh = aU((size_t)T*B*D);      ushort_t* xl = aU((size_t)T*B*D);
    ushort_t* hfh[2] = { aU((size_t)B*HE), aU((size_t)B*HE) };
    ushort_t* hfl[2] = { aU((size_t)B*HE), aU((size_t)B*HE) };
    ushort_t* hbh[2] = { aU((size_t)B*HE), aU((size_t)B*HE) };
    ushort_t* hbl[2] = { aU((size_t)B*HE), aU((size_t)B*HE) };
    ushort_t* zh = aU((size_t)B*L);        ushort_t* zl = aU((size_t)B*L);
    ushort_t* h0h[2] = { aU((size_t)B*L), aU((size_t)B*L) };
    ushort_t* h0l[2] = { aU((size_t)B*L), aU((size_t)B*L) };
    ushort_t* ftsH = aU((size_t)4*B*L);    ushort_t* ftsL = aU((size_t)4*B*L);
    ushort_t* featH = aU((size_t)4*B*L);   ushort_t* featL = aU((size_t)4*B*L);
    ushort_t* hd1h[2] = { aU((size_t)B*L), aU((size_t)B*L) };
    ushort_t* hd1l[2] = { aU((size_t)B*L), aU((size_t)B*L) };
    ushort_t* slabH = aU((size_t)T*B*L);   ushort_t* slabL = aU((size_t)T*B*L);
    float* cf   = aF((size_t)B*HE);
    float* cb   = aF((size_t)B*HE);
    float* zbuf = aF((size_t)B*HE);
    float* c0   = aF((size_t)B*L);
    float* c1   = aF((size_t)B*L);
    float* cd1  = aF((size_t)B*L);
    float* cd2  = aF((size_t)B*L);
    float* featF = aF((size_t)4*B*L);
    float* bEF = aF((size_t)4*HE);
    float* bEB = aF((size_t)4*HE);
    float* bC0 = aF((size_t)4*L);
    float* bC1 = aF((size_t)4*L);
    float* bD0 = aF((size_t)4*L);
    float* bD1 = aF((size_t)4*L);
    const size_t need = (size_t)(cur - (char*)d_ws);
    if (need > ws_size) return;

    // ==================== packing (single dispatch, output-major) ====================
    {
        PkAll pa{};
        int base = 0, i = 0;
        auto add = [&](const float* s, ushort_t* h, ushort_t* l, int Np, int K, int H) {
            pa.s[i++] = { s, h, l, K, H, base };
            base += Np * (K >> 3);
        };
        add(We_ih_f, WefIh, WefIl, 4*HE, D, HE);
        add(We_hh_f, WefHh, WefHl, 4*HE, HE, HE);
        add(We_ih_b, WebIh, WebIl, 4*HE, D, HE);
        add(We_hh_b, WebHh, WebHl, 4*HE, HE, HE);
        add(Wc_ih0, Wc0Ih, Wc0Il, 4*L, L, L);
        add(Wc_hh0, Wc0Hh, Wc0Hl, 4*L, L, L);
        add(Wc_ih1, Wc1Ih, Wc1Il, 4*L, L, L);
        add(Wc_hh1, Wc1Hh, Wc1Hl, 4*L, L, L);
        add(Wd_ih0, Wd0Ih, Wd0Il, 4*L, D+L, L);
        add(Wd_hh0, Wd0Hh, Wd0Hl, 4*L, L, L);
        add(Wd_ih1, Wd1Ih, Wd1Il, 4*L, L, L);
        add(Wd_hh1, Wd1Hh, Wd1Hl, 4*L, L, L);
        add(Wmu,  WmuH,  WmuL,  L, 2*HE, 0);
        add(Wstd, WstdH, WstdL, L, 2*HE, 0);
        add(Wcl,  WclH,  WclL,  L, L, 0);
        add(Wlog, WlogH, WlogL, D, L, 0);
        pa.total = base;
        pack_all<<<(pa.total + 255) / 256, 256, 0, stream>>>(pa);

        PbAll pb{};
        int bb = 0, k = 0;
        auto addb = [&](const float* b1, const float* b2, float* dst, int H) {
            pb.s[k++] = { b1, b2, dst, H, bb };
            bb += 4 * H;
        };
        addb(be_ih_f, be_hh_f, bEF, HE);
        addb(be_ih_b, be_hh_b, bEB, HE);
        addb(bc_ih0, bc_hh0, bC0, L);
        addb(bc_ih1, bc_hh1, bC1, L);
        addb(bd_ih0, bd_hh0, bD0, L);
        addb(bd_ih1, bd_hh1, bD1, L);
        pb.total = bb;
        pack_bias_all<<<(pb.total + 255) / 256, 256, 0, stream>>>(pb);
    }
    conv_x<<<(T*B*D/8 + 255) / 256, 256, 0, stream>>>(x, xh, xl);
    (void)hipMemsetAsync(zbuf, 0, (size_t)B * HE * sizeof(float), stream);

    // ---------- encoder (WIDE split-K: 64-row blocks, halved weight stream) ----------
    for (int t = 0; t < T; ++t) {
        MArgs f{};
        f.op[0] = { xh + (size_t)t*B*D, xl + (size_t)t*B*D, 16, 0, WefIh, WefIl, 16, 0, D };
        if (t) f.op[1] = { hfh[t&1], hfl[t&1], 32, 0, WefHh, WefHl, 32, 0, HE };
        f.ci0 = bEF; f.ld0 = 0;
        f.mode = 1;
        f.cin = t ? cf : zbuf; f.cinLd = HE;
        f.cout = cf; f.coutLd = HE;
        f.hHi = hfh[(t+1)&1]; f.hLo = hfl[(t+1)&1]; f.hLdT = 32;
        MArgs b = f;
        b.op[0] = { xh + (size_t)(T-1-t)*B*D, xl + (size_t)(T-1-t)*B*D, 16, 0, WebIh, WebIl, 16, 0, D };
        if (t) b.op[1] = { hbh[t&1], hbl[t&1], 32, 0, WebHh, WebHl, 32, 0, HE };
        b.ci0 = bEB;
        b.cin = t ? cb : zbuf;
        b.cout = cb;
        b.hHi = hbh[(t+1)&1]; b.hLo = hbl[(t+1)&1];
        gemm_sk<0,1><<<dim3((4*HE/64) * (B/64), 1, 2), 256, 0, stream>>>(f, b);
    }

    // ---------- latent ----------
    {
        MArgs m{};
        m.op[0] = { hfh[0], hfl[0], 32, 0, WmuH, WmuL, 64, 0, HE };
        m.op[1] = { hbh[0], hbl[0], 32, 0, WmuH, WmuL, 64, 32, HE };
        m.ci0 = bmu; m.ld0 = 0; m.mode = 0; m.out = mu_out; m.outLd = L;
        MArgs s = m;
        s.op[0].Whi = WstdH; s.op[0].Wlo = WstdL;
        s.op[1].Whi = WstdH; s.op[1].Wlo = WstdL;
        s.ci0 = bstd; s.out = std_out;
        gemm_t<3,1,1,1><<<dim3(L/64, B/16, 2), 64, 0, stream>>>(m, s);
        latent2<<<B, 64, 0, stream>>>(mu_out, std_out, eps, c0, c1, zh, zl);
    }

    // ---------- conductor (split-K MF2 WIDE=0, z-paired, XCD-swizzled) ----------
    auto condL1 = [&](int bar) {
        MArgs a{};
        a.op[0] = { zh, zl, 16, 0, Wc0Ih, Wc0Il, 16, 0, L };
        a.op[1] = { bar ? h0h[(bar-1)&1] : zh, bar ? h0l[(bar-1)&1] : zl, 16, 0, Wc0Hh, Wc0Hl, 16, 0, L };
        a.ci0 = bC0; a.ld0 = 0; a.mode = 1;
        a.cin = c0; a.cinLd = L; a.cout = c0; a.coutLd = L;
        a.hHi = h0h[bar&1]; a.hLo = h0l[bar&1]; a.hLdT = 16;
        return a;
    };
    auto condL2 = [&](int bar) {
        MArgs a2{};
        a2.op[0] = { h0h[bar&1], h0l[bar&1], 16, 0, Wc1Ih, Wc1Il, 16, 0, L };
        if (bar) a2.op[1] = { ftsH + (size_t)(bar-1)*B*L, ftsL + (size_t)(bar-1)*B*L, 16, 0, Wc1Hh, Wc1Hl, 16, 0, L };
        else     a2.op[1] = { zh, zl, 16, 0, Wc1Hh, Wc1Hl, 16, 0, L };
        a2.ci0 = bC1; a2.ld0 = 0; a2.mode = 1;
        a2.cin = c1; a2.cinLd = L; a2.cout = c1; a2.coutLd = L;
        a2.hHi = ftsH + (size_t)bar*B*L; a2.hLo = ftsL + (size_t)bar*B*L; a2.hLdT = 16;
        return a2;
    };
    {
        MArgs l1 = condL1(0);
        gemm_sk<2,0><<<dim3((4*L/64) * (B/32), 1, 1), 256, 0, stream>>>(l1, l1);
        for (int bar = 0; bar < 4; ++bar) {
            MArgs l2 = condL2(bar);
            if (bar + 1 < 4) {
                MArgs n1 = condL1(bar + 1);
                gemm_sk<2,0><<<dim3((4*L/64) * (B/32), 1, 2), 256, 0, stream>>>(l2, n1);
            } else {
                gemm_sk<2,0><<<dim3((4*L/64) * (B/32), 1, 1), 256, 0, stream>>>(l2, l2);
            }
        }
    }
    {   // feat: M = 4B rows (bar-major), K = L
        MArgs af{};
        af.op[0] = { ftsH, ftsL, 16, 0, WclH, WclL, 16, 0, L };
        af.ci0 = bcl; af.ld0 = 0; af.mode = 0;
        af.out = featF; af.outLd = L;
        af.pHi = featH; af.pLo = featL; af.pLdT = 16;
        gemm_t<3,1,1,1><<<dim3(L/64, 4*B/16, 1), 64, 0, stream>>>(af, af);
    }

    // ---------- decoder (split-K MF2 WIDE=0, z-paired g2(t) + g1(t+1), XCD-swizzled) ----------
    auto decG1 = [&](int t) {
        const int bar = t >> 4;
        const bool rs = (t & 15) == 0;
        MArgs g1{};
        if (t) g1.op[0] = { xh + (size_t)(t-1)*B*D, xl + (size_t)(t-1)*B*D, 16, 0, Wd0Ih, Wd0Il, 32, 0, D };
        g1.op[1] = { featH + (size_t)bar*B*L, featL + (size_t)bar*B*L, 16, 0, Wd0Ih, Wd0Il, 32, 16, L };
        if (rs) g1.op[2] = { featH + (size_t)bar*B*L, featL + (size_t)bar*B*L, 16, 0, Wd0Hh, Wd0Hl, 16, 0, L };
        else    g1.op[2] = { hd1h[(t-1)&1], hd1l[(t-1)&1], 16, 0, Wd0Hh, Wd0Hl, 16, 0, L };
        g1.ci0 = bD0; g1.ld0 = 0; g1.mode = 1;
        g1.cin = rs ? featF + (size_t)bar*B*L : cd1; g1.cinLd = L;
        g1.cout = cd1; g1.coutLd = L;
        g1.hHi = hd1h[t&1]; g1.hLo = hd1l[t&1]; g1.hLdT = 16;
        return g1;
    };
    auto decG2 = [&](int t) {
        const int bar = t >> 4;
        const bool rs = (t & 15) == 0;
        MArgs g2{};
        g2.op[0] = { hd1h[t&1], hd1l[t&1], 16, 0, Wd1Ih, Wd1Il, 16, 0, L };
        if (rs) g2.op[1] = { featH + (size_t)bar*B*L, featL + (size_t)bar*B*L, 16, 0, Wd1Hh, Wd1Hl, 16, 0, L };
        else    g2.op[1] = { slabH + (size_t)(t-1)*B*L, slabL + (size_t)(t-1)*B*L, 16, 0, Wd1Hh, Wd1Hl, 16, 0, L };
        g2.ci0 = bD1; g2.ld0 = 0; g2.mode = 1;
        g2.cin = rs ? featF + (size_t)bar*B*L : cd2; g2.cinLd = L;
        g2.cout = cd2; g2.coutLd = L;
        g2.hHi = slabH + (size_t)t*B*L; g2.hLo = slabL + (size_t)t*B*L; g2.hLdT = 16;
        return g2;
    };
    {
        MArgs g1 = decG1(0);
        gemm_sk<4,0><<<dim3((4*L/64) * (B/32), 1, 1), 256, 0, stream>>>(g1, g1);
        for (int t = 0; t < T; ++t) {
            MArgs g2 = decG2(t);
            if (t + 1 < T) {
                MArgs n1 = decG1(t + 1);
                gemm_sk<4,0><<<dim3((4*L/64) * (B/32), 1, 2), 256, 0, stream>>>(g2, n1);
            } else {
                gemm_sk<4,0><<<dim3((4*L/64) * (B/32), 1, 1), 256, 0, stream>>>(g2, g2);
            }
        }
    }

    // ---------- logits (batched, 64x256 tile) + softmax ----------
    {
        MArgs lg{};
        lg.op[0] = { slabH, slabL, 16, 0, WlogH, WlogL, 16, 0, L };
        lg.ci0 = blog; lg.ld0 = 0; lg.mode = 2;
        lg.out = prob_out; lg.outLd = D;
        gemm_t<5,2,2,4><<<dim3(D/256, T*B/64, 1), 512, 0, stream>>>(lg, lg);
    }
    softmax_all<<<B * T, 64, 0, stream>>>(prob_out, lab_out);
}

// Round 22
// 3296.831 us; speedup vs baseline: 1.0937x; 1.0022x over previous
//
#include <hip/hip_runtime.h>
#include <cstddef>
#include <cstdint>

static constexpr int B  = 256;
static constexpr int T  = 64;
static constexpr int D  = 512;
static constexpr int HE = 1024;
static constexpr int L  = 512;

typedef unsigned short ushort_t;
typedef __attribute__((ext_vector_type(8))) short short8;
typedef __attribute__((ext_vector_type(8))) unsigned short ushort8_t;
typedef __attribute__((ext_vector_type(8))) _Float16 f16x8;
typedef __attribute__((ext_vector_type(4))) float f32x4;
typedef __attribute__((ext_vector_type(4))) unsigned short ushort4_t;

static constexpr float LO_SCALE   = 2048.0f;
static constexpr float LO_UNSCALE = 4.8828125e-4f;   // 1/2048

__device__ __forceinline__ float sigmoidf_(float x) { return 1.0f / (1.0f + expf(-x)); }

struct hfp { ushort_t hi, lo; };
__device__ __forceinline__ hfp f16_split(float v) {
    _Float16 h = (_Float16)v;
    _Float16 l = (_Float16)((v - (float)h) * LO_SCALE);
    hfp r;
    r.hi = __builtin_bit_cast(ushort_t, h);
    r.lo = __builtin_bit_cast(ushort_t, l);
    return r;
}

// Fragment-major tile layout: 16 rows x 32 k per 512-elem tile.
__device__ __forceinline__ size_t tile_off(int m, int n, int ldt) {
    return ((size_t)(m >> 4) * ldt + (n >> 5)) * 512
         + (size_t)((((m & 15) + (((n >> 3) & 3) << 4)) << 3) + (n & 7));
}

// ======================= weight/bias packing (output-major, coalesced writes) ==========
struct PkSeg { const float* src; ushort_t* hi; ushort_t* lo; int K, H, base; };  // base in chunks
struct PkAll { PkSeg s[16]; int total; };

__global__ void pack_all(PkAll pa)
{
    int idx = blockIdx.x * 256 + threadIdx.x;
    if (idx >= pa.total) return;
    int si = 0;
#pragma unroll
    for (int i = 1; i < 16; ++i) if (idx >= pa.s[i].base) si = i;
    const PkSeg sg = pa.s[si];
    int c = idx - sg.base;
    int ldt = sg.K >> 5;
    int t = c >> 6;
    int lane = c & 63;
    int m15 = lane & 15;
    int kg  = lane >> 4;
    int p  = (t / ldt) * 16 + m15;
    int k0 = (t % ldt) * 32 + kg * 8;
    int srow = p;
    if (sg.H) srow = ((p >> 4) & 3) * sg.H + (p >> 6) * 16 + (p & 15);
    const float* s = sg.src + (size_t)srow * sg.K + k0;
    ushort8_t h, l;
#pragma unroll
    for (int j = 0; j < 8; ++j) {
        hfp a = f16_split(s[j]);
        h[j] = a.hi; l[j] = a.lo;
    }
    size_t off = (size_t)t * 512 + lane * 8;
    *(ushort8_t*)(sg.hi + off) = h;
    *(ushort8_t*)(sg.lo + off) = l;
}

struct PbSeg { const float* b1; const float* b2; float* dst; int H, base; };
struct PbAll { PbSeg s[6]; int total; };

__global__ void pack_bias_all(PbAll pb)
{
    int idx = blockIdx.x * 256 + threadIdx.x;
    if (idx >= pb.total) return;
    int si = 0;
#pragma unroll
    for (int i = 1; i < 6; ++i) if (idx >= pb.s[i].base) si = i;
    const PbSeg sg = pb.s[si];
    int p = idx - sg.base;
    int srow = ((p >> 4) & 3) * sg.H + (p >> 6) * 16 + (p & 15);
    sg.dst[p] = sg.b1[srow] + sg.b2[srow];
}

// x [B][T][D] fp32 -> per-t tiled f16 pair planes; output-major (coalesced writes).
__global__ void conv_x(const float* __restrict__ x, ushort_t* __restrict__ xh,
                       ushort_t* __restrict__ xl)
{
    int idx = blockIdx.x * 256 + threadIdx.x;
    if (idx >= T * B * D / 8) return;
    int slab = idx >> 14;
    int c2 = idx & 16383;
    int t2 = c2 >> 6;
    int lane = c2 & 63;
    int tr = t2 >> 4, tc = t2 & 15;
    int b  = tr * 16 + (lane & 15);
    int k0 = tc * 32 + (lane >> 4) * 8;
    const float* s = x + ((size_t)b * T + slab) * D + k0;
    ushort8_t h, l;
#pragma unroll
    for (int j = 0; j < 8; ++j) {
        hfp a = f16_split(s[j]);
        h[j] = a.hi; l[j] = a.lo;
    }
    size_t off = (size_t)slab * B * D + (size_t)t2 * 512 + lane * 8;
    *(ushort8_t*)(xh + off) = h;
    *(ushort8_t*)(xl + off) = l;
}

// ======================= fp16x3 MFMA GEMM (tiled operands) =======================
struct Op {
    const ushort_t *Ahi, *Alo; int ldtA, kt0A;
    const ushort_t *Whi, *Wlo; int ldtW, kt0W;
    int K;
};
struct MArgs {
    Op op[3];
    const float* ci0; int ld0;
    int mode;                        // 0 plain, 1 lstm, 2 plain + prob-permute rows
    const float* cin; int cinLd;
    float* cout; int coutLd;
    ushort_t *hHi, *hLo; int hLdT;
    float* out; int outLd;
    ushort_t *pHi, *pLo; int pLdT;
};

__device__ __forceinline__ f32x4 MFH(short8 a, short8 w, f32x4 c) {
    return __builtin_amdgcn_mfma_f32_16x16x32_f16(
        __builtin_bit_cast(f16x8, a), __builtin_bit_cast(f16x8, w), c, 0, 0, 0);
}

// ---------------- split-K GEMM, two geometries ----------------
// WIDE=0: 32 rows x 64 cols; 4 waves split K 4-ways (proven R12 config).
//   Shortest per-wave serial K-path => latency-bound chain phases + small-M GEMMs.
// WIDE=1: 64 rows x 64 cols; 4 waves = 2 m-pair groups x 2 k-halves.
//   Halves weight stream => BW-bound phases (encoder; R19 win, R20 falsified elsewhere).
// Grid flattened 1-D in x (XCD swizzle); blockIdx.y = coarse-M chunk (256 rows each).
template<int TAG, int WIDE>
__global__ __launch_bounds__(256) void gemm_sk(MArgs ga0, MArgs ga1)
{
    __shared__ float LV[4][2][4][4][64];   // [wave][mf][j][r][lane] = 32 KB
    const MArgs& ga = blockIdx.z ? ga1 : ga0;
    const int tid  = threadIdx.x;
    const int lane = tid & 63;
    const int wk   = tid >> 6;
    const int bid = blockIdx.x;
    int bx, by, m_w;
    if (WIDE) {
        bx = ((bid >> 5) << 3) | (bid & 7);
        by = (bid >> 3) & 3;
        m_w = (blockIdx.y * 4 + by) * 64;
    } else {
        bx = ((bid >> 6) << 3) | (bid & 7);
        by = (bid >> 3) & 7;
        m_w = (blockIdx.y * 8 + by) * 32;
    }
    const int n_w = bx * 64;
    const int l15 = lane & 15;
    const int mbase = (m_w >> 4) + (WIDE ? (wk & 1) * 2 : 0);

    f32x4 accH[2][4], accL[2][4];
#pragma unroll
    for (int mf = 0; mf < 2; ++mf)
#pragma unroll
        for (int j = 0; j < 4; ++j)
#pragma unroll
            for (int r = 0; r < 4; ++r) { accH[mf][j][r] = 0.0f; accL[mf][j][r] = 0.0f; }

    int NT = 0;
#pragma unroll
    for (int opi = 0; opi < 3; ++opi)
        if (ga.op[opi].Ahi && ga.op[opi].K > 0) NT += ga.op[opi].K >> 5;
    const int share = WIDE ? (NT >> 1) : (NT >> 2);
    int skip = (WIDE ? (wk >> 1) : wk) * share, cnt = share;

#pragma unroll 1
    for (int opi = 0; opi < 3 && cnt > 0; ++opi) {
        const Op o = ga.op[opi];
        if (o.Ahi == nullptr || o.K <= 0) continue;
        const int NK = o.K >> 5;
        if (skip >= NK) { skip -= NK; continue; }
        const int k0 = skip;
        const int k1 = (NK - k0 < cnt) ? NK : k0 + cnt;
        cnt -= (k1 - k0);
        skip = 0;

        const ushort_t *aHp[2], *aLp[2], *wHp[4], *wLp[4];
#pragma unroll
        for (int mf = 0; mf < 2; ++mf) {
            size_t ro = ((size_t)(mbase + mf) * o.ldtA + o.kt0A) * 512 + lane * 8;
            aHp[mf] = o.Ahi + ro; aLp[mf] = o.Alo + ro;
        }
#pragma unroll
        for (int j = 0; j < 4; ++j) {
            size_t ro = ((size_t)((n_w >> 4) + j) * o.ldtW + o.kt0W) * 512 + lane * 8;
            wHp[j] = o.Whi + ro; wLp[j] = o.Wlo + ro;
        }

        short8 A0[2], L0[2], W0[4], V0[4];
        short8 A1[2], L1[2], W1[4], V1[4];
        auto LD0 = [&](int ks) {
#pragma unroll
            for (int mf = 0; mf < 2; ++mf) {
                A0[mf] = *(const short8*)(aHp[mf] + (size_t)ks * 512);
                L0[mf] = *(const short8*)(aLp[mf] + (size_t)ks * 512);
            }
#pragma unroll
            for (int j = 0; j < 4; ++j) {
                W0[j] = *(const short8*)(wHp[j] + (size_t)ks * 512);
                V0[j] = *(const short8*)(wLp[j] + (size_t)ks * 512);
            }
        };
        auto LD1 = [&](int ks) {
#pragma unroll
            for (int mf = 0; mf < 2; ++mf) {
                A1[mf] = *(const short8*)(aHp[mf] + (size_t)ks * 512);
                L1[mf] = *(const short8*)(aLp[mf] + (size_t)ks * 512);
            }
#pragma unroll
            for (int j = 0; j < 4; ++j) {
                W1[j] = *(const short8*)(wHp[j] + (size_t)ks * 512);
                V1[j] = *(const short8*)(wLp[j] + (size_t)ks * 512);
            }
        };
        auto MM0 = [&]() {
#pragma unroll
            for (int mf = 0; mf < 2; ++mf)
#pragma unroll
                for (int j = 0; j < 4; ++j) {
                    accL[mf][j] = MFH(A0[mf], V0[j], accL[mf][j]);
                    accL[mf][j] = MFH(L0[mf], W0[j], accL[mf][j]);
                    accH[mf][j] = MFH(A0[mf], W0[j], accH[mf][j]);
                }
        };
        auto MM1 = [&]() {
#pragma unroll
            for (int mf = 0; mf < 2; ++mf)
#pragma unroll
                for (int j = 0; j < 4; ++j) {
                    accL[mf][j] = MFH(A1[mf], V1[j], accL[mf][j]);
                    accL[mf][j] = MFH(L1[mf], W1[j], accL[mf][j]);
                    accH[mf][j] = MFH(A1[mf], W1[j], accH[mf][j]);
                }
        };

        LD0(k0);
        int ks = k0;
        for (; ks + 2 < k1; ks += 2) {
            LD1(ks + 1);
            MM0();
            LD0(ks + 2);
            MM1();
        }
        if (ks + 1 < k1) { LD1(ks + 1); MM0(); MM1(); }
        else MM0();
    }

    // ---- fold lo into hi, store partials ----
#pragma unroll
    for (int mf = 0; mf < 2; ++mf)
#pragma unroll
        for (int j = 0; j < 4; ++j)
#pragma unroll
            for (int r = 0; r < 4; ++r)
                LV[wk][mf][j][r][lane] = accH[mf][j][r] + LO_UNSCALE * accL[mf][j][r];
    __syncthreads();

    if (WIDE) {
        // ---- reduce: wave wk handles local m-tile lt = wk; partials from
        //      waves {lt>>1, (lt>>1)+2} at mf = lt&1; r = 0..3 ----
        const int lt = wk;
        const int wb = lt >> 1;
        const int mfl = lt & 1;
#pragma unroll
        for (int r = 0; r < 4; ++r) {
            float g[4];
#pragma unroll
            for (int j = 0; j < 4; ++j) {
                float s = LV[wb][mfl][j][r][lane] + LV[wb + 2][mfl][j][r][lane];
                if (ga.ci0) s += ga.ci0[n_w + j * 16 + l15];
                g[j] = s;
            }
            const int m = m_w + lt * 16 + (lane >> 4) * 4 + r;
            if (ga.mode == 1) {
                const int n = (n_w >> 6) * 16 + l15;
                const float cold = ga.cin[(size_t)m * ga.cinLd + n];
                const float cn = sigmoidf_(g[1]) * cold + sigmoidf_(g[0]) * tanhf(g[2]);
                const float h  = sigmoidf_(g[3]) * tanhf(cn);
                ga.cout[(size_t)m * ga.coutLd + n] = cn;
                hfp hp = f16_split(h);
                size_t off = tile_off(m, n, ga.hLdT);
                ga.hHi[off] = hp.hi;
                ga.hLo[off] = hp.lo;
            } else {
#pragma unroll
                for (int j = 0; j < 4; ++j) {
                    const int p = n_w + j * 16 + l15;
                    int dst = m;
                    if (ga.mode == 2) dst = ((m & (B - 1)) << 6) + (m >> 8);
                    if (ga.out) ga.out[(size_t)dst * ga.outLd + p] = g[j];
                    if (ga.pHi) {
                        hfp vp = f16_split(g[j]);
                        size_t off = tile_off(m, p, ga.pLdT);
                        ga.pHi[off] = vp.hi;
                        ga.pLo[off] = vp.lo;
                    }
                }
            }
        }
    } else {
        // ---- reduce: wave wk handles mf = wk>>1, row-slots r = (wk&1)*2 + {0,1} ----
        const int mf = wk >> 1;
        const int rb = (wk & 1) * 2;
#pragma unroll
        for (int rr = 0; rr < 2; ++rr) {
            const int r = rb + rr;
            float g[4];
#pragma unroll
            for (int j = 0; j < 4; ++j) {
                float s = 0.0f;
#pragma unroll
                for (int w2 = 0; w2 < 4; ++w2) s += LV[w2][mf][j][r][lane];
                if (ga.ci0) s += ga.ci0[n_w + j * 16 + l15];
                g[j] = s;
            }
            const int m = m_w + mf * 16 + (lane >> 4) * 4 + r;
            if (ga.mode == 1) {
                const int n = (n_w >> 6) * 16 + l15;
                const float cold = ga.cin[(size_t)m * ga.cinLd + n];
                const float cn = sigmoidf_(g[1]) * cold + sigmoidf_(g[0]) * tanhf(g[2]);
                const float h  = sigmoidf_(g[3]) * tanhf(cn);
                ga.cout[(size_t)m * ga.coutLd + n] = cn;
                hfp hp = f16_split(h);
                size_t off = tile_off(m, n, ga.hLdT);
                ga.hHi[off] = hp.hi;
                ga.hLo[off] = hp.lo;
            } else {
#pragma unroll
                for (int j = 0; j < 4; ++j) {
                    const int p = n_w + j * 16 + l15;
                    int dst = m;
                    if (ga.mode == 2) dst = ((m & (B - 1)) << 6) + (m >> 8);
                    if (ga.out) ga.out[(size_t)dst * ga.outLd + p] = g[j];
                    if (ga.pHi) {
                        hfp vp = f16_split(g[j]);
                        size_t off = tile_off(m, p, ga.pLdT);
                        ga.pHi[off] = vp.hi;
                        ga.pLo[off] = vp.lo;
                    }
                }
            }
        }
    }
}

// layernorm(mu), softplus(std), z = mu+eps*std -> c0,c1 (fp32) and z tiled f16 pairs
__global__ void latent2(float* __restrict__ mu, float* __restrict__ sd,
                        const float* __restrict__ eps, float* __restrict__ c0,
                        float* __restrict__ c1, ushort_t* __restrict__ zh,
                        ushort_t* __restrict__ zl)
{
    const int b = blockIdx.x, l = threadIdx.x;
    float* mrow = mu + (size_t)b * L;
    float4 v0 = *(const float4*)(mrow + l * 4);
    float4 v1 = *(const float4*)(mrow + 256 + l * 4);
    float s = v0.x + v0.y + v0.z + v0.w + v1.x + v1.y + v1.z + v1.w;
    float q = v0.x * v0.x + v0.y * v0.y + v0.z * v0.z + v0.w * v0.w
            + v1.x * v1.x + v1.y * v1.y + v1.z * v1.z + v1.w * v1.w;
#pragma unroll
    for (int off = 32; off; off >>= 1) { s += __shfl_xor(s, off); q += __shfl_xor(q, off); }
    const float mean = s * (1.0f / 512.0f);
    const float var  = q * (1.0f / 512.0f) - mean * mean;
    const float inv  = rsqrtf(var + 1e-5f);
    v0.x = (v0.x - mean) * inv; v0.y = (v0.y - mean) * inv; v0.z = (v0.z - mean) * inv; v0.w = (v0.w - mean) * inv;
    v1.x = (v1.x - mean) * inv; v1.y = (v1.y - mean) * inv; v1.z = (v1.z - mean) * inv; v1.w = (v1.w - mean) * inv;
    *(float4*)(mrow + l * 4) = v0;
    *(float4*)(mrow + 256 + l * 4) = v1;

    float* srow = sd + (size_t)b * L;
    float4 s0 = *(const float4*)(srow + l * 4);
    float4 s1 = *(const float4*)(srow + 256 + l * 4);
    s0.x = fmaxf(s0.x, 0.0f) + log1pf(expf(-fabsf(s0.x)));
    s0.y = fmaxf(s0.y, 0.0f) + log1pf(expf(-fabsf(s0.y)));
    s0.z = fmaxf(s0.z, 0.0f) + log1pf(expf(-fabsf(s0.z)));
    s0.w = fmaxf(s0.w, 0.0f) + log1pf(expf(-fabsf(s0.w)));
    s1.x = fmaxf(s1.x, 0.0f) + log1pf(expf(-fabsf(s1.x)));
    s1.y = fmaxf(s1.y, 0.0f) + log1pf(expf(-fabsf(s1.y)));
    s1.z = fmaxf(s1.z, 0.0f) + log1pf(expf(-fabsf(s1.z)));
    s1.w = fmaxf(s1.w, 0.0f) + log1pf(expf(-fabsf(s1.w)));
    *(float4*)(srow + l * 4) = s0;
    *(float4*)(srow + 256 + l * 4) = s1;

    const float* erow = eps + (size_t)b * L;
    float4 e0 = *(const float4*)(erow + l * 4);
    float4 e1 = *(const float4*)(erow + 256 + l * 4);
    float4 z0, z1;
    z0.x = v0.x + e0.x * s0.x; z0.y = v0.y + e0.y * s0.y; z0.z = v0.z + e0.z * s0.z; z0.w = v0.w + e0.w * s0.w;
    z1.x = v1.x + e1.x * s1.x; z1.y = v1.y + e1.y * s1.y; z1.z = v1.z + e1.z * s1.z; z1.w = v1.w + e1.w * s1.w;
    *(float4*)(c0 + (size_t)b * L + l * 4) = z0;
    *(float4*)(c0 + (size_t)b * L + 256 + l * 4) = z1;
    *(float4*)(c1 + (size_t)b * L + l * 4) = z0;
    *(float4*)(c1 + (size_t)b * L + 256 + l * 4) = z1;
    ushort4_t h, lo;
    hfp a;
    a = f16_split(z0.x); h[0] = a.hi; lo[0] = a.lo;
    a = f16_split(z0.y); h[1] = a.hi; lo[1] = a.lo;
    a = f16_split(z0.z); h[2] = a.hi; lo[2] = a.lo;
    a = f16_split(z0.w); h[3] = a.hi; lo[3] = a.lo;
    size_t o0 = tile_off(b, l * 4, 16);
    *(ushort4_t*)(zh + o0) = h;
    *(ushort4_t*)(zl + o0) = lo;
    a = f16_split(z1.x); h[0] = a.hi; lo[0] = a.lo;
    a = f16_split(z1.y); h[1] = a.hi; lo[1] = a.lo;
    a = f16_split(z1.z); h[2] = a.hi; lo[2] = a.lo;
    a = f16_split(z1.w); h[3] = a.hi; lo[3] = a.lo;
    size_t o1 = tile_off(b, 256 + l * 4, 16);
    *(ushort4_t*)(zh + o1) = h;
    *(ushort4_t*)(zl + o1) = lo;
}

// in-place softmax + argmax over all B*T rows; one wave per row.
__global__ void softmax_all(float* __restrict__ prob, float* __restrict__ label)
{
    const int r = blockIdx.x, l = threadIdx.x;
    float* row = prob + (size_t)r * D;
    float4 x0 = *(const float4*)(row + l * 4);
    float4 x1 = *(const float4*)(row + 256 + l * 4);
    float m = x0.x; int mi = l * 4;
    { float v; int i;
      v = x0.y; i = l * 4 + 1;       if (v > m) { m = v; mi = i; }
      v = x0.z; i = l * 4 + 2;       if (v > m) { m = v; mi = i; }
      v = x0.w; i = l * 4 + 3;       if (v > m) { m = v; mi = i; }
      v = x1.x; i = 256 + l * 4;     if (v > m) { m = v; mi = i; }
      v = x1.y; i = 256 + l * 4 + 1; if (v > m) { m = v; mi = i; }
      v = x1.z; i = 256 + l * 4 + 2; if (v > m) { m = v; mi = i; }
      v = x1.w; i = 256 + l * 4 + 3; if (v > m) { m = v; mi = i; } }
#pragma unroll
    for (int off = 32; off; off >>= 1) {
        float om = __shfl_xor(m, off);
        int   oi = __shfl_xor(mi, off);
        if (om > m || (om == m && oi < mi)) { m = om; mi = oi; }
    }
    float4 e0, e1;
    e0.x = expf(x0.x - m); e0.y = expf(x0.y - m); e0.z = expf(x0.z - m); e0.w = expf(x0.w - m);
    e1.x = expf(x1.x - m); e1.y = expf(x1.y - m); e1.z = expf(x1.z - m); e1.w = expf(x1.w - m);
    float s = e0.x + e0.y + e0.z + e0.w + e1.x + e1.y + e1.z + e1.w;
#pragma unroll
    for (int off = 32; off; off >>= 1) s += __shfl_xor(s, off);
    const float inv = 1.0f / s;
    e0.x *= inv; e0.y *= inv; e0.z *= inv; e0.w *= inv;
    e1.x *= inv; e1.y *= inv; e1.z *= inv; e1.w *= inv;
    *(float4*)(row + l * 4) = e0;
    *(float4*)(row + 256 + l * 4) = e1;
    if (l == 0) label[r] = (float)mi;
}

// ---------------------------------------------------------------------------
extern "C" void kernel_launch(void* const* d_in, const int* in_sizes, int n_in,
                              void* d_out, int out_size, void* d_ws, size_t ws_size,
                              hipStream_t stream)
{
    const float* x       = (const float*)d_in[0];
    const float* eps     = (const float*)d_in[1];
    const float* We_ih_f = (const float*)d_in[2];
    const float* We_hh_f = (const float*)d_in[3];
    const float* be_ih_f = (const float*)d_in[4];
    const float* be_hh_f = (const float*)d_in[5];
    const float* We_ih_b = (const float*)d_in[6];
    const float* We_hh_b = (const float*)d_in[7];
    const float* be_ih_b = (const float*)d_in[8];
    const float* be_hh_b = (const float*)d_in[9];
    const float* Wmu     = (const float*)d_in[10];
    const float* bmu     = (const float*)d_in[11];
    const float* Wstd    = (const float*)d_in[12];
    const float* bstd    = (const float*)d_in[13];
    const float* Wc_ih0  = (const float*)d_in[14];
    const float* Wc_hh0  = (const float*)d_in[15];
    const float* bc_ih0  = (const float*)d_in[16];
    const float* bc_hh0  = (const float*)d_in[17];
    const float* Wc_ih1  = (const float*)d_in[18];
    const float* Wc_hh1  = (const float*)d_in[19];
    const float* bc_ih1  = (const float*)d_in[20];
    const float* bc_hh1  = (const float*)d_in[21];
    const float* Wcl     = (const float*)d_in[22];
    const float* bcl     = (const float*)d_in[23];
    const float* Wd_ih0  = (const float*)d_in[24];
    const float* Wd_hh0  = (const float*)d_in[25];
    const float* bd_ih0  = (const float*)d_in[26];
    const float* bd_hh0  = (const float*)d_in[27];
    const float* Wd_ih1  = (const float*)d_in[28];
    const float* Wd_hh1  = (const float*)d_in[29];
    const float* bd_ih1  = (const float*)d_in[30];
    const float* bd_hh1  = (const float*)d_in[31];
    const float* Wlog    = (const float*)d_in[32];
    const float* blog    = (const float*)d_in[33];
    (void)in_sizes; (void)n_in; (void)out_size;

    float* out      = (float*)d_out;
    float* prob_out = out;
    float* mu_out   = out + (size_t)B * T * D;
    float* std_out  = mu_out + (size_t)B * L;
    float* lab_out  = std_out + (size_t)B * L;

    // ---------------- workspace layout ----------------
    char* cur = (char*)d_ws;
    auto alignup = [&]() { cur = (char*)(((uintptr_t)cur + 255) & ~(uintptr_t)255); };
    auto aU = [&](size_t elems) { alignup(); ushort_t* p = (ushort_t*)cur; cur += elems * 2; return p; };
    auto aF = [&](size_t elems) { alignup(); float* p = (float*)cur; cur += elems * 4; return p; };

    ushort_t* WefIh = aU((size_t)4*HE*D);  ushort_t* WefIl = aU((size_t)4*HE*D);
    ushort_t* WefHh = aU((size_t)4*HE*HE); ushort_t* WefHl = aU((size_t)4*HE*HE);
    ushort_t* WebIh = aU((size_t)4*HE*D);  ushort_t* WebIl = aU((size_t)4*HE*D);
    ushort_t* WebHh = aU((size_t)4*HE*HE); ushort_t* WebHl = aU((size_t)4*HE*HE);
    ushort_t* Wc0Ih = aU((size_t)4*L*L);   ushort_t* Wc0Il = aU((size_t)4*L*L);
    ushort_t* Wc0Hh = aU((size_t)4*L*L);   ushort_t* Wc0Hl = aU((size_t)4*L*L);
    ushort_t* Wc1Ih = aU((size_t)4*L*L);   ushort_t* Wc1Il = aU((size_t)4*L*L);
    ushort_t* Wc1Hh = aU((size_t)4*L*L);   ushort_t* Wc1Hl = aU((size_t)4*L*L);
    ushort_t* Wd0Ih = aU((size_t)4*L*(D+L)); ushort_t* Wd0Il = aU((size_t)4*L*(D+L));
    ushort_t* Wd0Hh = aU((size_t)4*L*L);   ushort_t* Wd0Hl = aU((size_t)4*L*L);
    ushort_t* Wd1Ih = aU((size_t)4*L*L);   ushort_t* Wd1Il = aU((size_t)4*L*L);
    ushort_t* Wd1Hh = aU((size_t)4*L*L);   ushort_t* Wd1Hl = aU((size_t)4*L*L);
    ushort_t* WmuH  = aU((size_t)L*2*HE);  ushort_t* WmuL  = aU((size_t)L*2*HE);
    ushort_t* WstdH = aU((size_t)L*2*HE);  ushort_t* WstdL = aU((size_t)L*2*HE);
    ushort_t* WclH  = aU((size_t)L*L);     ushort_t* WclL  = aU((size_t)L*L);
    ushort_t* WlogH = aU((size_t)D*L);     ushort_t* WlogL = aU((size_t)D*L);
    ushort_t* xh = aU((size_t)T*B*D);      ushort_t* xl = aU((size_t)T*B*D);
    ushort_t* hfh[2] = { aU((size_t)B*HE), aU((size_t)B*HE) };
    ushort_t* hfl[2] = { aU((size_t)B*HE), aU((size_t)B*HE) };
    ushort_t* hbh[2] = { aU((size_t)B*HE), aU((size_t)B*HE) };
    ushort_t* hbl[2] = { aU((size_t)B*HE), aU((size_t)B*HE) };
    ushort_t* zh = aU((size_t)B*L);        ushort_t* zl = aU((size_t)B*L);
    ushort_t* h0h[2] = { aU((size_t)B*L), aU((size_t)B*L) };
    ushort_t* h0l[2] = { aU((size_t)B*L), aU((size_t)B*L) };
    ushort_t* ftsH = aU((size_t)4*B*L);    ushort_t* ftsL = aU((size_t)4*B*L);
    ushort_t* featH = aU((size_t)4*B*L);   ushort_t* featL = aU((size_t)4*B*L);
    ushort_t* hd1h[2] = { aU((size_t)B*L), aU((size_t)B*L) };
    ushort_t* hd1l[2] = { aU((size_t)B*L), aU((size_t)B*L) };
    ushort_t* slabH = aU((size_t)T*B*L);   ushort_t* slabL = aU((size_t)T*B*L);
    float* cf   = aF((size_t)B*HE);
    float* cb   = aF((size_t)B*HE);
    float* zbuf = aF((size_t)B*HE);
    float* c0   = aF((size_t)B*L);
    float* c1   = aF((size_t)B*L);
    float* cd1  = aF((size_t)B*L);
    float* cd2  = aF((size_t)B*L);
    float* featF = aF((size_t)4*B*L);
    float* bEF = aF((size_t)4*HE);
    float* bEB = aF((size_t)4*HE);
    float* bC0 = aF((size_t)4*L);
    float* bC1 = aF((size_t)4*L);
    float* bD0 = aF((size_t)4*L);
    float* bD1 = aF((size_t)4*L);
    const size_t need = (size_t)(cur - (char*)d_ws);
    if (need > ws_size) return;

    // ==================== packing (single dispatch, output-major) ====================
    {
        PkAll pa{};
        int base = 0, i = 0;
        auto add = [&](const float* s, ushort_t* h, ushort_t* l, int Np, int K, int H) {
            pa.s[i++] = { s, h, l, K, H, base };
            base += Np * (K >> 3);
        };
        add(We_ih_f, WefIh, WefIl, 4*HE, D, HE);
        add(We_hh_f, WefHh, WefHl, 4*HE, HE, HE);
        add(We_ih_b, WebIh, WebIl, 4*HE, D, HE);
        add(We_hh_b, WebHh, WebHl, 4*HE, HE, HE);
        add(Wc_ih0, Wc0Ih, Wc0Il, 4*L, L, L);
        add(Wc_hh0, Wc0Hh, Wc0Hl, 4*L, L, L);
        add(Wc_ih1, Wc1Ih, Wc1Il, 4*L, L, L);
        add(Wc_hh1, Wc1Hh, Wc1Hl, 4*L, L, L);
        add(Wd_ih0, Wd0Ih, Wd0Il, 4*L, D+L, L);
        add(Wd_hh0, Wd0Hh, Wd0Hl, 4*L, L, L);
        add(Wd_ih1, Wd1Ih, Wd1Il, 4*L, L, L);
        add(Wd_hh1, Wd1Hh, Wd1Hl, 4*L, L, L);
        add(Wmu,  WmuH,  WmuL,  L, 2*HE, 0);
        add(Wstd, WstdH, WstdL, L, 2*HE, 0);
        add(Wcl,  WclH,  WclL,  L, L, 0);
        add(Wlog, WlogH, WlogL, D, L, 0);
        pa.total = base;
        pack_all<<<(pa.total + 255) / 256, 256, 0, stream>>>(pa);

        PbAll pb{};
        int bb = 0, k = 0;
        auto addb = [&](const float* b1, const float* b2, float* dst, int H) {
            pb.s[k++] = { b1, b2, dst, H, bb };
            bb += 4 * H;
        };
        addb(be_ih_f, be_hh_f, bEF, HE);
        addb(be_ih_b, be_hh_b, bEB, HE);
        addb(bc_ih0, bc_hh0, bC0, L);
        addb(bc_ih1, bc_hh1, bC1, L);
        addb(bd_ih0, bd_hh0, bD0, L);
        addb(bd_ih1, bd_hh1, bD1, L);
        pb.total = bb;
        pack_bias_all<<<(pb.total + 255) / 256, 256, 0, stream>>>(pb);
    }
    conv_x<<<(T*B*D/8 + 255) / 256, 256, 0, stream>>>(x, xh, xl);
    (void)hipMemsetAsync(zbuf, 0, (size_t)B * HE * sizeof(float), stream);

    // ---------- encoder (WIDE split-K: 64-row blocks, halved weight stream) ----------
    for (int t = 0; t < T; ++t) {
        MArgs f{};
        f.op[0] = { xh + (size_t)t*B*D, xl + (size_t)t*B*D, 16, 0, WefIh, WefIl, 16, 0, D };
        if (t) f.op[1] = { hfh[t&1], hfl[t&1], 32, 0, WefHh, WefHl, 32, 0, HE };
        f.ci0 = bEF; f.ld0 = 0;
        f.mode = 1;
        f.cin = t ? cf : zbuf; f.cinLd = HE;
        f.cout = cf; f.coutLd = HE;
        f.hHi = hfh[(t+1)&1]; f.hLo = hfl[(t+1)&1]; f.hLdT = 32;
        MArgs b = f;
        b.op[0] = { xh + (size_t)(T-1-t)*B*D, xl + (size_t)(T-1-t)*B*D, 16, 0, WebIh, WebIl, 16, 0, D };
        if (t) b.op[1] = { hbh[t&1], hbl[t&1], 32, 0, WebHh, WebHl, 32, 0, HE };
        b.ci0 = bEB;
        b.cin = t ? cb : zbuf;
        b.cout = cb;
        b.hHi = hbh[(t+1)&1]; b.hLo = hbl[(t+1)&1];
        gemm_sk<0,1><<<dim3((4*HE/64) * (B/64), 1, 2), 256, 0, stream>>>(f, b);
    }

    // ---------- latent (split-K: 4-wave blocks replace 1-wave gemm_t; R21 ord-72 fix) ----------
    {
        MArgs m{};
        m.op[0] = { hfh[0], hfl[0], 32, 0, WmuH, WmuL, 64, 0, HE };
        m.op[1] = { hbh[0], hbl[0], 32, 0, WmuH, WmuL, 64, 32, HE };
        m.ci0 = bmu; m.ld0 = 0; m.mode = 0; m.out = mu_out; m.outLd = L;
        MArgs s = m;
        s.op[0].Whi = WstdH; s.op[0].Wlo = WstdL;
        s.op[1].Whi = WstdH; s.op[1].Wlo = WstdL;
        s.ci0 = bstd; s.out = std_out;
        gemm_sk<3,0><<<dim3((L/64) * (B/32), 1, 2), 256, 0, stream>>>(m, s);
        latent2<<<B, 64, 0, stream>>>(mu_out, std_out, eps, c0, c1, zh, zl);
    }

    // ---------- conductor (split-K MF2 WIDE=0, z-paired, XCD-swizzled) ----------
    auto condL1 = [&](int bar) {
        MArgs a{};
        a.op[0] = { zh, zl, 16, 0, Wc0Ih, Wc0Il, 16, 0, L };
        a.op[1] = { bar ? h0h[(bar-1)&1] : zh, bar ? h0l[(bar-1)&1] : zl, 16, 0, Wc0Hh, Wc0Hl, 16, 0, L };
        a.ci0 = bC0; a.ld0 = 0; a.mode = 1;
        a.cin = c0; a.cinLd = L; a.cout = c0; a.coutLd = L;
        a.hHi = h0h[bar&1]; a.hLo = h0l[bar&1]; a.hLdT = 16;
        return a;
    };
    auto condL2 = [&](int bar) {
        MArgs a2{};
        a2.op[0] = { h0h[bar&1], h0l[bar&1], 16, 0, Wc1Ih, Wc1Il, 16, 0, L };
        if (bar) a2.op[1] = { ftsH + (size_t)(bar-1)*B*L, ftsL + (size_t)(bar-1)*B*L, 16, 0, Wc1Hh, Wc1Hl, 16, 0, L };
        else     a2.op[1] = { zh, zl, 16, 0, Wc1Hh, Wc1Hl, 16, 0, L };
        a2.ci0 = bC1; a2.ld0 = 0; a2.mode = 1;
        a2.cin = c1; a2.cinLd = L; a2.cout = c1; a2.coutLd = L;
        a2.hHi = ftsH + (size_t)bar*B*L; a2.hLo = ftsL + (size_t)bar*B*L; a2.hLdT = 16;
        return a2;
    };
    {
        MArgs l1 = condL1(0);
        gemm_sk<2,0><<<dim3((4*L/64) * (B/32), 1, 1), 256, 0, stream>>>(l1, l1);
        for (int bar = 0; bar < 4; ++bar) {
            MArgs l2 = condL2(bar);
            if (bar + 1 < 4) {
                MArgs n1 = condL1(bar + 1);
                gemm_sk<2,0><<<dim3((4*L/64) * (B/32), 1, 2), 256, 0, stream>>>(l2, n1);
            } else {
                gemm_sk<2,0><<<dim3((4*L/64) * (B/32), 1, 1), 256, 0, stream>>>(l2, l2);
            }
        }
    }
    {   // feat: M = 4B rows (bar-major), K = L; split-K w/ 4 coarse-M chunks
        MArgs af{};
        af.op[0] = { ftsH, ftsL, 16, 0, WclH, WclL, 16, 0, L };
        af.ci0 = bcl; af.ld0 = 0; af.mode = 0;
        af.out = featF; af.outLd = L;
        af.pHi = featH; af.pLo = featL; af.pLdT = 16;
        gemm_sk<5,0><<<dim3((L/64) * 8, 4*B/256, 1), 256, 0, stream>>>(af, af);
    }

    // ---------- decoder (split-K MF2 WIDE=0, z-paired g2(t) + g1(t+1), XCD-swizzled) ----------
    auto decG1 = [&](int t) {
        const int bar = t >> 4;
        const bool rs = (t & 15) == 0;
        MArgs g1{};
        if (t) g1.op[0] = { xh + (size_t)(t-1)*B*D, xl + (size_t)(t-1)*B*D, 16, 0, Wd0Ih, Wd0Il, 32, 0, D };
        g1.op[1] = { featH + (size_t)bar*B*L, featL + (size_t)bar*B*L, 16, 0, Wd0Ih, Wd0Il, 32, 16, L };
        if (rs) g1.op[2] = { featH + (size_t)bar*B*L, featL + (size_t)bar*B*L, 16, 0, Wd0Hh, Wd0Hl, 16, 0, L };
        else    g1.op[2] = { hd1h[(t-1)&1], hd1l[(t-1)&1], 16, 0, Wd0Hh, Wd0Hl, 16, 0, L };
        g1.ci0 = bD0; g1.ld0 = 0; g1.mode = 1;
        g1.cin = rs ? featF + (size_t)bar*B*L : cd1; g1.cinLd = L;
        g1.cout = cd1; g1.coutLd = L;
        g1.hHi = hd1h[t&1]; g1.hLo = hd1l[t&1]; g1.hLdT = 16;
        return g1;
    };
    auto decG2 = [&](int t) {
        const int bar = t >> 4;
        const bool rs = (t & 15) == 0;
        MArgs g2{};
        g2.op[0] = { hd1h[t&1], hd1l[t&1], 16, 0, Wd1Ih, Wd1Il, 16, 0, L };
        if (rs) g2.op[1] = { featH + (size_t)bar*B*L, featL + (size_t)bar*B*L, 16, 0, Wd1Hh, Wd1Hl, 16, 0, L };
        else    g2.op[1] = { slabH + (size_t)(t-1)*B*L, slabL + (size_t)(t-1)*B*L, 16, 0, Wd1Hh, Wd1Hl, 16, 0, L };
        g2.ci0 = bD1; g2.ld0 = 0; g2.mode = 1;
        g2.cin = rs ? featF + (size_t)bar*B*L : cd2; g2.cinLd = L;
        g2.cout = cd2; g2.coutLd = L;
        g2.hHi = slabH + (size_t)t*B*L; g2.hLo = slabL + (size_t)t*B*L; g2.hLdT = 16;
        return g2;
    };
    {
        MArgs g1 = decG1(0);
        gemm_sk<4,0><<<dim3((4*L/64) * (B/32), 1, 1), 256, 0, stream>>>(g1, g1);
        for (int t = 0; t < T; ++t) {
            MArgs g2 = decG2(t);
            if (t + 1 < T) {
                MArgs n1 = decG1(t + 1);
                gemm_sk<4,0><<<dim3((4*L/64) * (B/32), 1, 2), 256, 0, stream>>>(g2, n1);
            } else {
                gemm_sk<4,0><<<dim3((4*L/64) * (B/32), 1, 1), 256, 0, stream>>>(g2, g2);
            }
        }
    }

    // ---------- logits (split-K, 64 coarse-M chunks, 4096 blocks) + softmax ----------
    {
        MArgs lg{};
        lg.op[0] = { slabH, slabL, 16, 0, WlogH, WlogL, 16, 0, L };
        lg.ci0 = blog; lg.ld0 = 0; lg.mode = 2;
        lg.out = prob_out; lg.outLd = D;
        gemm_sk<6,0><<<dim3((D/64) * 8, T*B/256, 1), 256, 0, stream>>>(lg, lg);
    }
    softmax_all<<<B * T, 64, 0, stream>>>(prob_out, lab_out);
}

// Round 23
// 3265.020 us; speedup vs baseline: 1.1044x; 1.0097x over previous
//
#include <hip/hip_runtime.h>
#include <cstddef>
#include <cstdint>

static constexpr int B  = 256;
static constexpr int T  = 64;
static constexpr int D  = 512;
static constexpr int HE = 1024;
static constexpr int L  = 512;

typedef unsigned short ushort_t;
typedef __attribute__((ext_vector_type(8))) short short8;
typedef __attribute__((ext_vector_type(8))) unsigned short ushort8_t;
typedef __attribute__((ext_vector_type(8))) _Float16 f16x8;
typedef __attribute__((ext_vector_type(4))) float f32x4;
typedef __attribute__((ext_vector_type(4))) unsigned short ushort4_t;

static constexpr float LO_SCALE   = 2048.0f;
static constexpr float LO_UNSCALE = 4.8828125e-4f;   // 1/2048

__device__ __forceinline__ float sigmoidf_(float x) { return 1.0f / (1.0f + expf(-x)); }

struct hfp { ushort_t hi, lo; };
__device__ __forceinline__ hfp f16_split(float v) {
    _Float16 h = (_Float16)v;
    _Float16 l = (_Float16)((v - (float)h) * LO_SCALE);
    hfp r;
    r.hi = __builtin_bit_cast(ushort_t, h);
    r.lo = __builtin_bit_cast(ushort_t, l);
    return r;
}

// Fragment-major tile layout: 16 rows x 32 k per 512-elem tile.
__device__ __forceinline__ size_t tile_off(int m, int n, int ldt) {
    return ((size_t)(m >> 4) * ldt + (n >> 5)) * 512
         + (size_t)((((m & 15) + (((n >> 3) & 3) << 4)) << 3) + (n & 7));
}

// ======================= weight/bias packing (output-major, coalesced writes) ==========
struct PkSeg { const float* src; ushort_t* hi; ushort_t* lo; int K, H, base; };  // base in chunks
struct PkAll { PkSeg s[16]; int total; };

__global__ void pack_all(PkAll pa)
{
    int idx = blockIdx.x * 256 + threadIdx.x;
    if (idx >= pa.total) return;
    int si = 0;
#pragma unroll
    for (int i = 1; i < 16; ++i) if (idx >= pa.s[i].base) si = i;
    const PkSeg sg = pa.s[si];
    int c = idx - sg.base;
    int ldt = sg.K >> 5;
    int t = c >> 6;
    int lane = c & 63;
    int m15 = lane & 15;
    int kg  = lane >> 4;
    int p  = (t / ldt) * 16 + m15;
    int k0 = (t % ldt) * 32 + kg * 8;
    int srow = p;
    if (sg.H) srow = ((p >> 4) & 3) * sg.H + (p >> 6) * 16 + (p & 15);
    const float* s = sg.src + (size_t)srow * sg.K + k0;
    ushort8_t h, l;
#pragma unroll
    for (int j = 0; j < 8; ++j) {
        hfp a = f16_split(s[j]);
        h[j] = a.hi; l[j] = a.lo;
    }
    size_t off = (size_t)t * 512 + lane * 8;
    *(ushort8_t*)(sg.hi + off) = h;
    *(ushort8_t*)(sg.lo + off) = l;
}

struct PbSeg { const float* b1; const float* b2; float* dst; int H, base; };
struct PbAll { PbSeg s[6]; int total; };

__global__ void pack_bias_all(PbAll pb)
{
    int idx = blockIdx.x * 256 + threadIdx.x;
    if (idx >= pb.total) return;
    int si = 0;
#pragma unroll
    for (int i = 1; i < 6; ++i) if (idx >= pb.s[i].base) si = i;
    const PbSeg sg = pb.s[si];
    int p = idx - sg.base;
    int srow = ((p >> 4) & 3) * sg.H + (p >> 6) * 16 + (p & 15);
    sg.dst[p] = sg.b1[srow] + sg.b2[srow];
}

// x [B][T][D] fp32 -> per-t tiled f16 pair planes; output-major (coalesced writes).
__global__ void conv_x(const float* __restrict__ x, ushort_t* __restrict__ xh,
                       ushort_t* __restrict__ xl)
{
    int idx = blockIdx.x * 256 + threadIdx.x;
    if (idx >= T * B * D / 8) return;
    int slab = idx >> 14;
    int c2 = idx & 16383;
    int t2 = c2 >> 6;
    int lane = c2 & 63;
    int tr = t2 >> 4, tc = t2 & 15;
    int b  = tr * 16 + (lane & 15);
    int k0 = tc * 32 + (lane >> 4) * 8;
    const float* s = x + ((size_t)b * T + slab) * D + k0;
    ushort8_t h, l;
#pragma unroll
    for (int j = 0; j < 8; ++j) {
        hfp a = f16_split(s[j]);
        h[j] = a.hi; l[j] = a.lo;
    }
    size_t off = (size_t)slab * B * D + (size_t)t2 * 512 + lane * 8;
    *(ushort8_t*)(xh + off) = h;
    *(ushort8_t*)(xl + off) = l;
}

// ======================= fp16x3 MFMA GEMM (tiled operands) =======================
struct Op {
    const ushort_t *Ahi, *Alo; int ldtA, kt0A;
    const ushort_t *Whi, *Wlo; int ldtW, kt0W;
    int K;
};
struct MArgs {
    Op op[3];
    const float* ci0; int ld0;
    int mode;                        // 0 plain, 1 lstm, 2 plain + prob-permute rows
    const float* cin; int cinLd;
    float* cout; int coutLd;
    ushort_t *hHi, *hLo; int hLdT;
    float* out; int outLd;
    ushort_t *pHi, *pLo; int pLdT;
};

__device__ __forceinline__ f32x4 MFH(short8 a, short8 w, f32x4 c) {
    return __builtin_amdgcn_mfma_f32_16x16x32_f16(
        __builtin_bit_cast(f16x8, a), __builtin_bit_cast(f16x8, w), c, 0, 0, 0);
}

// ---------------- split-K GEMM, two geometries ----------------
// WIDE=0: 32 rows x 64 cols; 4 waves split K 4-ways (proven R12 config).
//   Shortest per-wave serial K-path => latency-bound chain phases + small-M GEMMs.
// WIDE=1: 64 rows x 64 cols; 4 waves = 2 m-pair groups x 2 k-halves.
//   Halves weight stream => BW-bound phases (encoder; R19 win, R20 falsified elsewhere).
// NOTE (R22): narrow 64-col tile => A re-read amplification = N/64; do NOT use for
// large-M x small-K shapes with wide N reuse (logits: 8x amp, FETCH 36->132 MB).
// Grid flattened 1-D in x (XCD swizzle); blockIdx.y = coarse-M chunk (256 rows each).
template<int TAG, int WIDE>
__global__ __launch_bounds__(256) void gemm_sk(MArgs ga0, MArgs ga1)
{
    __shared__ float LV[4][2][4][4][64];   // [wave][mf][j][r][lane] = 32 KB
    const MArgs& ga = blockIdx.z ? ga1 : ga0;
    const int tid  = threadIdx.x;
    const int lane = tid & 63;
    const int wk   = tid >> 6;
    const int bid = blockIdx.x;
    int bx, by, m_w;
    if (WIDE) {
        bx = ((bid >> 5) << 3) | (bid & 7);
        by = (bid >> 3) & 3;
        m_w = (blockIdx.y * 4 + by) * 64;
    } else {
        bx = ((bid >> 6) << 3) | (bid & 7);
        by = (bid >> 3) & 7;
        m_w = (blockIdx.y * 8 + by) * 32;
    }
    const int n_w = bx * 64;
    const int l15 = lane & 15;
    const int mbase = (m_w >> 4) + (WIDE ? (wk & 1) * 2 : 0);

    f32x4 accH[2][4], accL[2][4];
#pragma unroll
    for (int mf = 0; mf < 2; ++mf)
#pragma unroll
        for (int j = 0; j < 4; ++j)
#pragma unroll
            for (int r = 0; r < 4; ++r) { accH[mf][j][r] = 0.0f; accL[mf][j][r] = 0.0f; }

    int NT = 0;
#pragma unroll
    for (int opi = 0; opi < 3; ++opi)
        if (ga.op[opi].Ahi && ga.op[opi].K > 0) NT += ga.op[opi].K >> 5;
    const int share = WIDE ? (NT >> 1) : (NT >> 2);
    int skip = (WIDE ? (wk >> 1) : wk) * share, cnt = share;

#pragma unroll 1
    for (int opi = 0; opi < 3 && cnt > 0; ++opi) {
        const Op o = ga.op[opi];
        if (o.Ahi == nullptr || o.K <= 0) continue;
        const int NK = o.K >> 5;
        if (skip >= NK) { skip -= NK; continue; }
        const int k0 = skip;
        const int k1 = (NK - k0 < cnt) ? NK : k0 + cnt;
        cnt -= (k1 - k0);
        skip = 0;

        const ushort_t *aHp[2], *aLp[2], *wHp[4], *wLp[4];
#pragma unroll
        for (int mf = 0; mf < 2; ++mf) {
            size_t ro = ((size_t)(mbase + mf) * o.ldtA + o.kt0A) * 512 + lane * 8;
            aHp[mf] = o.Ahi + ro; aLp[mf] = o.Alo + ro;
        }
#pragma unroll
        for (int j = 0; j < 4; ++j) {
            size_t ro = ((size_t)((n_w >> 4) + j) * o.ldtW + o.kt0W) * 512 + lane * 8;
            wHp[j] = o.Whi + ro; wLp[j] = o.Wlo + ro;
        }

        short8 A0[2], L0[2], W0[4], V0[4];
        short8 A1[2], L1[2], W1[4], V1[4];
        auto LD0 = [&](int ks) {
#pragma unroll
            for (int mf = 0; mf < 2; ++mf) {
                A0[mf] = *(const short8*)(aHp[mf] + (size_t)ks * 512);
                L0[mf] = *(const short8*)(aLp[mf] + (size_t)ks * 512);
            }
#pragma unroll
            for (int j = 0; j < 4; ++j) {
                W0[j] = *(const short8*)(wHp[j] + (size_t)ks * 512);
                V0[j] = *(const short8*)(wLp[j] + (size_t)ks * 512);
            }
        };
        auto LD1 = [&](int ks) {
#pragma unroll
            for (int mf = 0; mf < 2; ++mf) {
                A1[mf] = *(const short8*)(aHp[mf] + (size_t)ks * 512);
                L1[mf] = *(const short8*)(aLp[mf] + (size_t)ks * 512);
            }
#pragma unroll
            for (int j = 0; j < 4; ++j) {
                W1[j] = *(const short8*)(wHp[j] + (size_t)ks * 512);
                V1[j] = *(const short8*)(wLp[j] + (size_t)ks * 512);
            }
        };
        auto MM0 = [&]() {
#pragma unroll
            for (int mf = 0; mf < 2; ++mf)
#pragma unroll
                for (int j = 0; j < 4; ++j) {
                    accL[mf][j] = MFH(A0[mf], V0[j], accL[mf][j]);
                    accL[mf][j] = MFH(L0[mf], W0[j], accL[mf][j]);
                    accH[mf][j] = MFH(A0[mf], W0[j], accH[mf][j]);
                }
        };
        auto MM1 = [&]() {
#pragma unroll
            for (int mf = 0; mf < 2; ++mf)
#pragma unroll
                for (int j = 0; j < 4; ++j) {
                    accL[mf][j] = MFH(A1[mf], V1[j], accL[mf][j]);
                    accL[mf][j] = MFH(L1[mf], W1[j], accL[mf][j]);
                    accH[mf][j] = MFH(A1[mf], W1[j], accH[mf][j]);
                }
        };

        LD0(k0);
        int ks = k0;
        for (; ks + 2 < k1; ks += 2) {
            LD1(ks + 1);
            MM0();
            LD0(ks + 2);
            MM1();
        }
        if (ks + 1 < k1) { LD1(ks + 1); MM0(); MM1(); }
        else MM0();
    }

    // ---- fold lo into hi, store partials ----
#pragma unroll
    for (int mf = 0; mf < 2; ++mf)
#pragma unroll
        for (int j = 0; j < 4; ++j)
#pragma unroll
            for (int r = 0; r < 4; ++r)
                LV[wk][mf][j][r][lane] = accH[mf][j][r] + LO_UNSCALE * accL[mf][j][r];
    __syncthreads();

    if (WIDE) {
        // ---- reduce: wave wk handles local m-tile lt = wk; partials from
        //      waves {lt>>1, (lt>>1)+2} at mf = lt&1; r = 0..3 ----
        const int lt = wk;
        const int wb = lt >> 1;
        const int mfl = lt & 1;
#pragma unroll
        for (int r = 0; r < 4; ++r) {
            float g[4];
#pragma unroll
            for (int j = 0; j < 4; ++j) {
                float s = LV[wb][mfl][j][r][lane] + LV[wb + 2][mfl][j][r][lane];
                if (ga.ci0) s += ga.ci0[n_w + j * 16 + l15];
                g[j] = s;
            }
            const int m = m_w + lt * 16 + (lane >> 4) * 4 + r;
            if (ga.mode == 1) {
                const int n = (n_w >> 6) * 16 + l15;
                const float cold = ga.cin[(size_t)m * ga.cinLd + n];
                const float cn = sigmoidf_(g[1]) * cold + sigmoidf_(g[0]) * tanhf(g[2]);
                const float h  = sigmoidf_(g[3]) * tanhf(cn);
                ga.cout[(size_t)m * ga.coutLd + n] = cn;
                hfp hp = f16_split(h);
                size_t off = tile_off(m, n, ga.hLdT);
                ga.hHi[off] = hp.hi;
                ga.hLo[off] = hp.lo;
            } else {
#pragma unroll
                for (int j = 0; j < 4; ++j) {
                    const int p = n_w + j * 16 + l15;
                    int dst = m;
                    if (ga.mode == 2) dst = ((m & (B - 1)) << 6) + (m >> 8);
                    if (ga.out) ga.out[(size_t)dst * ga.outLd + p] = g[j];
                    if (ga.pHi) {
                        hfp vp = f16_split(g[j]);
                        size_t off = tile_off(m, p, ga.pLdT);
                        ga.pHi[off] = vp.hi;
                        ga.pLo[off] = vp.lo;
                    }
                }
            }
        }
    } else {
        // ---- reduce: wave wk handles mf = wk>>1, row-slots r = (wk&1)*2 + {0,1} ----
        const int mf = wk >> 1;
        const int rb = (wk & 1) * 2;
#pragma unroll
        for (int rr = 0; rr < 2; ++rr) {
            const int r = rb + rr;
            float g[4];
#pragma unroll
            for (int j = 0; j < 4; ++j) {
                float s = 0.0f;
#pragma unroll
                for (int w2 = 0; w2 < 4; ++w2) s += LV[w2][mf][j][r][lane];
                if (ga.ci0) s += ga.ci0[n_w + j * 16 + l15];
                g[j] = s;
            }
            const int m = m_w + mf * 16 + (lane >> 4) * 4 + r;
            if (ga.mode == 1) {
                const int n = (n_w >> 6) * 16 + l15;
                const float cold = ga.cin[(size_t)m * ga.cinLd + n];
                const float cn = sigmoidf_(g[1]) * cold + sigmoidf_(g[0]) * tanhf(g[2]);
                const float h  = sigmoidf_(g[3]) * tanhf(cn);
                ga.cout[(size_t)m * ga.coutLd + n] = cn;
                hfp hp = f16_split(h);
                size_t off = tile_off(m, n, ga.hLdT);
                ga.hHi[off] = hp.hi;
                ga.hLo[off] = hp.lo;
            } else {
#pragma unroll
                for (int j = 0; j < 4; ++j) {
                    const int p = n_w + j * 16 + l15;
                    int dst = m;
                    if (ga.mode == 2) dst = ((m & (B - 1)) << 6) + (m >> 8);
                    if (ga.out) ga.out[(size_t)dst * ga.outLd + p] = g[j];
                    if (ga.pHi) {
                        hfp vp = f16_split(g[j]);
                        size_t off = tile_off(m, p, ga.pLdT);
                        ga.pHi[off] = vp.hi;
                        ga.pLo[off] = vp.lo;
                    }
                }
            }
        }
    }
}

// ---------------- register-path GEMM (logits: wide 256-col tile, 2x A-amp) ----------------
template<int TAG, int MF, int WM, int WN>
__global__ __launch_bounds__(WM * WN * 64) void gemm_t(MArgs ga0, MArgs ga1)
{
    const MArgs& ga = blockIdx.z ? ga1 : ga0;
    const int lane = threadIdx.x & 63;
    const int wid  = threadIdx.x >> 6;
    const int wy = wid / WN, wx = wid % WN;
    const int m_w = blockIdx.y * (WM * MF * 16) + wy * MF * 16;
    const int n_w = blockIdx.x * (WN * 64) + wx * 64;
    const int l15 = lane & 15;
    const int rB  = (lane >> 4) * 4;

    f32x4 accH[MF][4];
    f32x4 accL[MF][4];
#pragma unroll
    for (int mf = 0; mf < MF; ++mf)
#pragma unroll
        for (int j = 0; j < 4; ++j) {
            const int p = n_w + j * 16 + l15;
#pragma unroll
            for (int r = 0; r < 4; ++r) {
                float v = 0.0f;
                if (ga.ci0) v += ga.ci0[(size_t)(m_w + mf * 16 + rB + r) * ga.ld0 + p];
                accH[mf][j][r] = v;
                accL[mf][j][r] = 0.0f;
            }
        }

#pragma unroll 1
    for (int opi = 0; opi < 3; ++opi) {
        const Op o = ga.op[opi];
        if (o.Ahi == nullptr || o.K <= 0) continue;
        const ushort_t *aH[MF], *aL[MF], *wH[4], *wL[4];
#pragma unroll
        for (int mf = 0; mf < MF; ++mf) {
            size_t ro = ((size_t)((m_w >> 4) + mf) * o.ldtA + o.kt0A) * 512 + lane * 8;
            aH[mf] = o.Ahi + ro; aL[mf] = o.Alo + ro;
        }
#pragma unroll
        for (int j = 0; j < 4; ++j) {
            size_t ro = ((size_t)((n_w >> 4) + j) * o.ldtW + o.kt0W) * 512 + lane * 8;
            wH[j] = o.Whi + ro; wL[j] = o.Wlo + ro;
        }
        const int NK = o.K >> 5;

        auto LD = [&](short8* ah, short8* al, short8* wh, short8* wl, int ks) {
#pragma unroll
            for (int mf = 0; mf < MF; ++mf) {
                ah[mf] = *(const short8*)(aH[mf] + (size_t)ks * 512);
                al[mf] = *(const short8*)(aL[mf] + (size_t)ks * 512);
            }
#pragma unroll
            for (int j = 0; j < 4; ++j) {
                wh[j] = *(const short8*)(wH[j] + (size_t)ks * 512);
                wl[j] = *(const short8*)(wL[j] + (size_t)ks * 512);
            }
        };
        auto MM = [&](short8* ah, short8* al, short8* wh, short8* wl) {
#pragma unroll
            for (int mf = 0; mf < MF; ++mf)
#pragma unroll
                for (int j = 0; j < 4; ++j) {
                    accL[mf][j] = MFH(ah[mf], wl[j], accL[mf][j]);
                    accL[mf][j] = MFH(al[mf], wh[j], accL[mf][j]);
                    accH[mf][j] = MFH(ah[mf], wh[j], accH[mf][j]);
                }
        };

        short8 A0[MF], L0[MF], W0[4], V0[4];
        short8 A1[MF], L1[MF], W1[4], V1[4];
        LD(A0, L0, W0, V0, 0);
        int ks = 0;
        for (; ks + 2 < NK; ks += 2) {
            LD(A1, L1, W1, V1, ks + 1);
            MM(A0, L0, W0, V0);
            LD(A0, L0, W0, V0, ks + 2);
            MM(A1, L1, W1, V1);
        }
        LD(A1, L1, W1, V1, ks + 1);
        MM(A0, L0, W0, V0);
        MM(A1, L1, W1, V1);
    }

    if (ga.mode == 1) {
        const int n = (n_w >> 6) * 16 + l15;
#pragma unroll
        for (int mf = 0; mf < MF; ++mf)
#pragma unroll
            for (int r = 0; r < 4; ++r) {
                const int m = m_w + mf * 16 + rB + r;
                const float gi = accH[mf][0][r] + LO_UNSCALE * accL[mf][0][r];
                const float gf = accH[mf][1][r] + LO_UNSCALE * accL[mf][1][r];
                const float gg = accH[mf][2][r] + LO_UNSCALE * accL[mf][2][r];
                const float go = accH[mf][3][r] + LO_UNSCALE * accL[mf][3][r];
                const float cold = ga.cin[(size_t)m * ga.cinLd + n];
                const float cn = sigmoidf_(gf) * cold + sigmoidf_(gi) * tanhf(gg);
                const float h  = sigmoidf_(go) * tanhf(cn);
                ga.cout[(size_t)m * ga.coutLd + n] = cn;
                hfp hp = f16_split(h);
                size_t off = tile_off(m, n, ga.hLdT);
                ga.hHi[off] = hp.hi;
                ga.hLo[off] = hp.lo;
            }
    } else {
#pragma unroll
        for (int mf = 0; mf < MF; ++mf)
#pragma unroll
            for (int j = 0; j < 4; ++j) {
                const int p = n_w + j * 16 + l15;
#pragma unroll
                for (int r = 0; r < 4; ++r) {
                    const int m = m_w + mf * 16 + rB + r;
                    const float v = accH[mf][j][r] + LO_UNSCALE * accL[mf][j][r];
                    int dst = m;
                    if (ga.mode == 2) dst = ((m & (B - 1)) << 6) + (m >> 8);
                    if (ga.out) ga.out[(size_t)dst * ga.outLd + p] = v;
                    if (ga.pHi) {
                        hfp vp = f16_split(v);
                        size_t off = tile_off(m, p, ga.pLdT);
                        ga.pHi[off] = vp.hi;
                        ga.pLo[off] = vp.lo;
                    }
                }
            }
    }
}

// layernorm(mu), softplus(std), z = mu+eps*std -> c0,c1 (fp32) and z tiled f16 pairs
__global__ void latent2(float* __restrict__ mu, float* __restrict__ sd,
                        const float* __restrict__ eps, float* __restrict__ c0,
                        float* __restrict__ c1, ushort_t* __restrict__ zh,
                        ushort_t* __restrict__ zl)
{
    const int b = blockIdx.x, l = threadIdx.x;
    float* mrow = mu + (size_t)b * L;
    float4 v0 = *(const float4*)(mrow + l * 4);
    float4 v1 = *(const float4*)(mrow + 256 + l * 4);
    float s = v0.x + v0.y + v0.z + v0.w + v1.x + v1.y + v1.z + v1.w;
    float q = v0.x * v0.x + v0.y * v0.y + v0.z * v0.z + v0.w * v0.w
            + v1.x * v1.x + v1.y * v1.y + v1.z * v1.z + v1.w * v1.w;
#pragma unroll
    for (int off = 32; off; off >>= 1) { s += __shfl_xor(s, off); q += __shfl_xor(q, off); }
    const float mean = s * (1.0f / 512.0f);
    const float var  = q * (1.0f / 512.0f) - mean * mean;
    const float inv  = rsqrtf(var + 1e-5f);
    v0.x = (v0.x - mean) * inv; v0.y = (v0.y - mean) * inv; v0.z = (v0.z - mean) * inv; v0.w = (v0.w - mean) * inv;
    v1.x = (v1.x - mean) * inv; v1.y = (v1.y - mean) * inv; v1.z = (v1.z - mean) * inv; v1.w = (v1.w - mean) * inv;
    *(float4*)(mrow + l * 4) = v0;
    *(float4*)(mrow + 256 + l * 4) = v1;

    float* srow = sd + (size_t)b * L;
    float4 s0 = *(const float4*)(srow + l * 4);
    float4 s1 = *(const float4*)(srow + 256 + l * 4);
    s0.x = fmaxf(s0.x, 0.0f) + log1pf(expf(-fabsf(s0.x)));
    s0.y = fmaxf(s0.y, 0.0f) + log1pf(expf(-fabsf(s0.y)));
    s0.z = fmaxf(s0.z, 0.0f) + log1pf(expf(-fabsf(s0.z)));
    s0.w = fmaxf(s0.w, 0.0f) + log1pf(expf(-fabsf(s0.w)));
    s1.x = fmaxf(s1.x, 0.0f) + log1pf(expf(-fabsf(s1.x)));
    s1.y = fmaxf(s1.y, 0.0f) + log1pf(expf(-fabsf(s1.y)));
    s1.z = fmaxf(s1.z, 0.0f) + log1pf(expf(-fabsf(s1.z)));
    s1.w = fmaxf(s1.w, 0.0f) + log1pf(expf(-fabsf(s1.w)));
    *(float4*)(srow + l * 4) = s0;
    *(float4*)(srow + 256 + l * 4) = s1;

    const float* erow = eps + (size_t)b * L;
    float4 e0 = *(const float4*)(erow + l * 4);
    float4 e1 = *(const float4*)(erow + 256 + l * 4);
    float4 z0, z1;
    z0.x = v0.x + e0.x * s0.x; z0.y = v0.y + e0.y * s0.y; z0.z = v0.z + e0.z * s0.z; z0.w = v0.w + e0.w * s0.w;
    z1.x = v1.x + e1.x * s1.x; z1.y = v1.y + e1.y * s1.y; z1.z = v1.z + e1.z * s1.z; z1.w = v1.w + e1.w * s1.w;
    *(float4*)(c0 + (size_t)b * L + l * 4) = z0;
    *(float4*)(c0 + (size_t)b * L + 256 + l * 4) = z1;
    *(float4*)(c1 + (size_t)b * L + l * 4) = z0;
    *(float4*)(c1 + (size_t)b * L + 256 + l * 4) = z1;
    ushort4_t h, lo;
    hfp a;
    a = f16_split(z0.x); h[0] = a.hi; lo[0] = a.lo;
    a = f16_split(z0.y); h[1] = a.hi; lo[1] = a.lo;
    a = f16_split(z0.z); h[2] = a.hi; lo[2] = a.lo;
    a = f16_split(z0.w); h[3] = a.hi; lo[3] = a.lo;
    size_t o0 = tile_off(b, l * 4, 16);
    *(ushort4_t*)(zh + o0) = h;
    *(ushort4_t*)(zl + o0) = lo;
    a = f16_split(z1.x); h[0] = a.hi; lo[0] = a.lo;
    a = f16_split(z1.y); h[1] = a.hi; lo[1] = a.lo;
    a = f16_split(z1.z); h[2] = a.hi; lo[2] = a.lo;
    a = f16_split(z1.w); h[3] = a.hi; lo[3] = a.lo;
    size_t o1 = tile_off(b, 256 + l * 4, 16);
    *(ushort4_t*)(zh + o1) = h;
    *(ushort4_t*)(zl + o1) = lo;
}

// in-place softmax + argmax over all B*T rows; one wave per row.
__global__ void softmax_all(float* __restrict__ prob, float* __restrict__ label)
{
    const int r = blockIdx.x, l = threadIdx.x;
    float* row = prob + (size_t)r * D;
    float4 x0 = *(const float4*)(row + l * 4);
    float4 x1 = *(const float4*)(row + 256 + l * 4);
    float m = x0.x; int mi = l * 4;
    { float v; int i;
      v = x0.y; i = l * 4 + 1;       if (v > m) { m = v; mi = i; }
      v = x0.z; i = l * 4 + 2;       if (v > m) { m = v; mi = i; }
      v = x0.w; i = l * 4 + 3;       if (v > m) { m = v; mi = i; }
      v = x1.x; i = 256 + l * 4;     if (v > m) { m = v; mi = i; }
      v = x1.y; i = 256 + l * 4 + 1; if (v > m) { m = v; mi = i; }
      v = x1.z; i = 256 + l * 4 + 2; if (v > m) { m = v; mi = i; }
      v = x1.w; i = 256 + l * 4 + 3; if (v > m) { m = v; mi = i; } }
#pragma unroll
    for (int off = 32; off; off >>= 1) {
        float om = __shfl_xor(m, off);
        int   oi = __shfl_xor(mi, off);
        if (om > m || (om == m && oi < mi)) { m = om; mi = oi; }
    }
    float4 e0, e1;
    e0.x = expf(x0.x - m); e0.y = expf(x0.y - m); e0.z = expf(x0.z - m); e0.w = expf(x0.w - m);
    e1.x = expf(x1.x - m); e1.y = expf(x1.y - m); e1.z = expf(x1.z - m); e1.w = expf(x1.w - m);
    float s = e0.x + e0.y + e0.z + e0.w + e1.x + e1.y + e1.z + e1.w;
#pragma unroll
    for (int off = 32; off; off >>= 1) s += __shfl_xor(s, off);
    const float inv = 1.0f / s;
    e0.x *= inv; e0.y *= inv; e0.z *= inv; e0.w *= inv;
    e1.x *= inv; e1.y *= inv; e1.z *= inv; e1.w *= inv;
    *(float4*)(row + l * 4) = e0;
    *(float4*)(row + 256 + l * 4) = e1;
    if (l == 0) label[r] = (float)mi;
}

// ---------------------------------------------------------------------------
extern "C" void kernel_launch(void* const* d_in, const int* in_sizes, int n_in,
                              void* d_out, int out_size, void* d_ws, size_t ws_size,
                              hipStream_t stream)
{
    const float* x       = (const float*)d_in[0];
    const float* eps     = (const float*)d_in[1];
    const float* We_ih_f = (const float*)d_in[2];
    const float* We_hh_f = (const float*)d_in[3];
    const float* be_ih_f = (const float*)d_in[4];
    const float* be_hh_f = (const float*)d_in[5];
    const float* We_ih_b = (const float*)d_in[6];
    const float* We_hh_b = (const float*)d_in[7];
    const float* be_ih_b = (const float*)d_in[8];
    const float* be_hh_b = (const float*)d_in[9];
    const float* Wmu     = (const float*)d_in[10];
    const float* bmu     = (const float*)d_in[11];
    const float* Wstd    = (const float*)d_in[12];
    const float* bstd    = (const float*)d_in[13];
    const float* Wc_ih0  = (const float*)d_in[14];
    const float* Wc_hh0  = (const float*)d_in[15];
    const float* bc_ih0  = (const float*)d_in[16];
    const float* bc_hh0  = (const float*)d_in[17];
    const float* Wc_ih1  = (const float*)d_in[18];
    const float* Wc_hh1  = (const float*)d_in[19];
    const float* bc_ih1  = (const float*)d_in[20];
    const float* bc_hh1  = (const float*)d_in[21];
    const float* Wcl     = (const float*)d_in[22];
    const float* bcl     = (const float*)d_in[23];
    const float* Wd_ih0  = (const float*)d_in[24];
    const float* Wd_hh0  = (const float*)d_in[25];
    const float* bd_ih0  = (const float*)d_in[26];
    const float* bd_hh0  = (const float*)d_in[27];
    const float* Wd_ih1  = (const float*)d_in[28];
    const float* Wd_hh1  = (const float*)d_in[29];
    const float* bd_ih1  = (const float*)d_in[30];
    const float* bd_hh1  = (const float*)d_in[31];
    const float* Wlog    = (const float*)d_in[32];
    const float* blog    = (const float*)d_in[33];
    (void)in_sizes; (void)n_in; (void)out_size;

    float* out      = (float*)d_out;
    float* prob_out = out;
    float* mu_out   = out + (size_t)B * T * D;
    float* std_out  = mu_out + (size_t)B * L;
    float* lab_out  = std_out + (size_t)B * L;

    // ---------------- workspace layout ----------------
    char* cur = (char*)d_ws;
    auto alignup = [&]() { cur = (char*)(((uintptr_t)cur + 255) & ~(uintptr_t)255); };
    auto aU = [&](size_t elems) { alignup(); ushort_t* p = (ushort_t*)cur; cur += elems * 2; return p; };
    auto aF = [&](size_t elems) { alignup(); float* p = (float*)cur; cur += elems * 4; return p; };

    ushort_t* WefIh = aU((size_t)4*HE*D);  ushort_t* WefIl = aU((size_t)4*HE*D);
    ushort_t* WefHh = aU((size_t)4*HE*HE); ushort_t* WefHl = aU((size_t)4*HE*HE);
    ushort_t* WebIh = aU((size_t)4*HE*D);  ushort_t* WebIl = aU((size_t)4*HE*D);
    ushort_t* WebHh = aU((size_t)4*HE*HE); ushort_t* WebHl = aU((size_t)4*HE*HE);
    ushort_t* Wc0Ih = aU((size_t)4*L*L);   ushort_t* Wc0Il = aU((size_t)4*L*L);
    ushort_t* Wc0Hh = aU((size_t)4*L*L);   ushort_t* Wc0Hl = aU((size_t)4*L*L);
    ushort_t* Wc1Ih = aU((size_t)4*L*L);   ushort_t* Wc1Il = aU((size_t)4*L*L);
    ushort_t* Wc1Hh = aU((size_t)4*L*L);   ushort_t* Wc1Hl = aU((size_t)4*L*L);
    ushort_t* Wd0Ih = aU((size_t)4*L*(D+L)); ushort_t* Wd0Il = aU((size_t)4*L*(D+L));
    ushort_t* Wd0Hh = aU((size_t)4*L*L);   ushort_t* Wd0Hl = aU((size_t)4*L*L);
    ushort_t* Wd1Ih = aU((size_t)4*L*L);   ushort_t* Wd1Il = aU((size_t)4*L*L);
    ushort_t* Wd1Hh = aU((size_t)4*L*L);   ushort_t* Wd1Hl = aU((size_t)4*L*L);
    ushort_t* WmuH  = aU((size_t)L*2*HE);  ushort_t* WmuL  = aU((size_t)L*2*HE);
    ushort_t* WstdH = aU((size_t)L*2*HE);  ushort_t* WstdL = aU((size_t)L*2*HE);
    ushort_t* WclH  = aU((size_t)L*L);     ushort_t* WclL  = aU((size_t)L*L);
    ushort_t* WlogH = aU((size_t)D*L);     ushort_t* WlogL = aU((size_t)D*L);
    ushort_t* xh = aU((size_t)T*B*D);      ushort_t* xl = aU((size_t)T*B*D);
    ushort_t* hfh[2] = { aU((size_t)B*HE), aU((size_t)B*HE) };
    ushort_t* hfl[2] = { aU((size_t)B*HE), aU((size_t)B*HE) };
    ushort_t* hbh[2] = { aU((size_t)B*HE), aU((size_t)B*HE) };
    ushort_t* hbl[2] = { aU((size_t)B*HE), aU((size_t)B*HE) };
    ushort_t* zh = aU((size_t)B*L);        ushort_t* zl = aU((size_t)B*L);
    ushort_t* h0h[2] = { aU((size_t)B*L), aU((size_t)B*L) };
    ushort_t* h0l[2] = { aU((size_t)B*L), aU((size_t)B*L) };
    ushort_t* ftsH = aU((size_t)4*B*L);    ushort_t* ftsL = aU((size_t)4*B*L);
    ushort_t* featH = aU((size_t)4*B*L);   ushort_t* featL = aU((size_t)4*B*L);
    ushort_t* hd1h[2] = { aU((size_t)B*L), aU((size_t)B*L) };
    ushort_t* hd1l[2] = { aU((size_t)B*L), aU((size_t)B*L) };
    ushort_t* slabH = aU((size_t)T*B*L);   ushort_t* slabL = aU((size_t)T*B*L);
    float* cf   = aF((size_t)B*HE);
    float* cb   = aF((size_t)B*HE);
    float* zbuf = aF((size_t)B*HE);
    float* c0   = aF((size_t)B*L);
    float* c1   = aF((size_t)B*L);
    float* cd1  = aF((size_t)B*L);
    float* cd2  = aF((size_t)B*L);
    float* featF = aF((size_t)4*B*L);
    float* bEF = aF((size_t)4*HE);
    float* bEB = aF((size_t)4*HE);
    float* bC0 = aF((size_t)4*L);
    float* bC1 = aF((size_t)4*L);
    float* bD0 = aF((size_t)4*L);
    float* bD1 = aF((size_t)4*L);
    const size_t need = (size_t)(cur - (char*)d_ws);
    if (need > ws_size) return;

    // ==================== packing (single dispatch, output-major) ====================
    {
        PkAll pa{};
        int base = 0, i = 0;
        auto add = [&](const float* s, ushort_t* h, ushort_t* l, int Np, int K, int H) {
            pa.s[i++] = { s, h, l, K, H, base };
            base += Np * (K >> 3);
        };
        add(We_ih_f, WefIh, WefIl, 4*HE, D, HE);
        add(We_hh_f, WefHh, WefHl, 4*HE, HE, HE);
        add(We_ih_b, WebIh, WebIl, 4*HE, D, HE);
        add(We_hh_b, WebHh, WebHl, 4*HE, HE, HE);
        add(Wc_ih0, Wc0Ih, Wc0Il, 4*L, L, L);
        add(Wc_hh0, Wc0Hh, Wc0Hl, 4*L, L, L);
        add(Wc_ih1, Wc1Ih, Wc1Il, 4*L, L, L);
        add(Wc_hh1, Wc1Hh, Wc1Hl, 4*L, L, L);
        add(Wd_ih0, Wd0Ih, Wd0Il, 4*L, D+L, L);
        add(Wd_hh0, Wd0Hh, Wd0Hl, 4*L, L, L);
        add(Wd_ih1, Wd1Ih, Wd1Il, 4*L, L, L);
        add(Wd_hh1, Wd1Hh, Wd1Hl, 4*L, L, L);
        add(Wmu,  WmuH,  WmuL,  L, 2*HE, 0);
        add(Wstd, WstdH, WstdL, L, 2*HE, 0);
        add(Wcl,  WclH,  WclL,  L, L, 0);
        add(Wlog, WlogH, WlogL, D, L, 0);
        pa.total = base;
        pack_all<<<(pa.total + 255) / 256, 256, 0, stream>>>(pa);

        PbAll pb{};
        int bb = 0, k = 0;
        auto addb = [&](const float* b1, const float* b2, float* dst, int H) {
            pb.s[k++] = { b1, b2, dst, H, bb };
            bb += 4 * H;
        };
        addb(be_ih_f, be_hh_f, bEF, HE);
        addb(be_ih_b, be_hh_b, bEB, HE);
        addb(bc_ih0, bc_hh0, bC0, L);
        addb(bc_ih1, bc_hh1, bC1, L);
        addb(bd_ih0, bd_hh0, bD0, L);
        addb(bd_ih1, bd_hh1, bD1, L);
        pb.total = bb;
        pack_bias_all<<<(pb.total + 255) / 256, 256, 0, stream>>>(pb);
    }
    conv_x<<<(T*B*D/8 + 255) / 256, 256, 0, stream>>>(x, xh, xl);
    (void)hipMemsetAsync(zbuf, 0, (size_t)B * HE * sizeof(float), stream);

    // ---------- encoder (WIDE split-K: 64-row blocks, halved weight stream) ----------
    for (int t = 0; t < T; ++t) {
        MArgs f{};
        f.op[0] = { xh + (size_t)t*B*D, xl + (size_t)t*B*D, 16, 0, WefIh, WefIl, 16, 0, D };
        if (t) f.op[1] = { hfh[t&1], hfl[t&1], 32, 0, WefHh, WefHl, 32, 0, HE };
        f.ci0 = bEF; f.ld0 = 0;
        f.mode = 1;
        f.cin = t ? cf : zbuf; f.cinLd = HE;
        f.cout = cf; f.coutLd = HE;
        f.hHi = hfh[(t+1)&1]; f.hLo = hfl[(t+1)&1]; f.hLdT = 32;
        MArgs b = f;
        b.op[0] = { xh + (size_t)(T-1-t)*B*D, xl + (size_t)(T-1-t)*B*D, 16, 0, WebIh, WebIl, 16, 0, D };
        if (t) b.op[1] = { hbh[t&1], hbl[t&1], 32, 0, WebHh, WebHl, 32, 0, HE };
        b.ci0 = bEB;
        b.cin = t ? cb : zbuf;
        b.cout = cb;
        b.hHi = hbh[(t+1)&1]; b.hLo = hbl[(t+1)&1];
        gemm_sk<0,1><<<dim3((4*HE/64) * (B/64), 1, 2), 256, 0, stream>>>(f, b);
    }

    // ---------- latent (split-K: 4-wave blocks; R21 ord-72 fix) ----------
    {
        MArgs m{};
        m.op[0] = { hfh[0], hfl[0], 32, 0, WmuH, WmuL, 64, 0, HE };
        m.op[1] = { hbh[0], hbl[0], 32, 0, WmuH, WmuL, 64, 32, HE };
        m.ci0 = bmu; m.ld0 = 0; m.mode = 0; m.out = mu_out; m.outLd = L;
        MArgs s = m;
        s.op[0].Whi = WstdH; s.op[0].Wlo = WstdL;
        s.op[1].Whi = WstdH; s.op[1].Wlo = WstdL;
        s.ci0 = bstd; s.out = std_out;
        gemm_sk<3,0><<<dim3((L/64) * (B/32), 1, 2), 256, 0, stream>>>(m, s);
        latent2<<<B, 64, 0, stream>>>(mu_out, std_out, eps, c0, c1, zh, zl);
    }

    // ---------- conductor (split-K MF2 WIDE=0, z-paired, XCD-swizzled) ----------
    auto condL1 = [&](int bar) {
        MArgs a{};
        a.op[0] = { zh, zl, 16, 0, Wc0Ih, Wc0Il, 16, 0, L };
        a.op[1] = { bar ? h0h[(bar-1)&1] : zh, bar ? h0l[(bar-1)&1] : zl, 16, 0, Wc0Hh, Wc0Hl, 16, 0, L };
        a.ci0 = bC0; a.ld0 = 0; a.mode = 1;
        a.cin = c0; a.cinLd = L; a.cout = c0; a.coutLd = L;
        a.hHi = h0h[bar&1]; a.hLo = h0l[bar&1]; a.hLdT = 16;
        return a;
    };
    auto condL2 = [&](int bar) {
        MArgs a2{};
        a2.op[0] = { h0h[bar&1], h0l[bar&1], 16, 0, Wc1Ih, Wc1Il, 16, 0, L };
        if (bar) a2.op[1] = { ftsH + (size_t)(bar-1)*B*L, ftsL + (size_t)(bar-1)*B*L, 16, 0, Wc1Hh, Wc1Hl, 16, 0, L };
        else     a2.op[1] = { zh, zl, 16, 0, Wc1Hh, Wc1Hl, 16, 0, L };
        a2.ci0 = bC1; a2.ld0 = 0; a2.mode = 1;
        a2.cin = c1; a2.cinLd = L; a2.cout = c1; a2.coutLd = L;
        a2.hHi = ftsH + (size_t)bar*B*L; a2.hLo = ftsL + (size_t)bar*B*L; a2.hLdT = 16;
        return a2;
    };
    {
        MArgs l1 = condL1(0);
        gemm_sk<2,0><<<dim3((4*L/64) * (B/32), 1, 1), 256, 0, stream>>>(l1, l1);
        for (int bar = 0; bar < 4; ++bar) {
            MArgs l2 = condL2(bar);
            if (bar + 1 < 4) {
                MArgs n1 = condL1(bar + 1);
                gemm_sk<2,0><<<dim3((4*L/64) * (B/32), 1, 2), 256, 0, stream>>>(l2, n1);
            } else {
                gemm_sk<2,0><<<dim3((4*L/64) * (B/32), 1, 1), 256, 0, stream>>>(l2, l2);
            }
        }
    }
    {   // feat: M = 4B rows (bar-major), K = L; split-K w/ 4 coarse-M chunks
        MArgs af{};
        af.op[0] = { ftsH, ftsL, 16, 0, WclH, WclL, 16, 0, L };
        af.ci0 = bcl; af.ld0 = 0; af.mode = 0;
        af.out = featF; af.outLd = L;
        af.pHi = featH; af.pLo = featL; af.pLdT = 16;
        gemm_sk<5,0><<<dim3((L/64) * 8, 4*B/256, 1), 256, 0, stream>>>(af, af);
    }

    // ---------- decoder (split-K MF2 WIDE=0, z-paired g2(t) + g1(t+1), XCD-swizzled) ----------
    auto decG1 = [&](int t) {
        const int bar = t >> 4;
        const bool rs = (t & 15) == 0;
        MArgs g1{};
        if (t) g1.op[0] = { xh + (size_t)(t-1)*B*D, xl + (size_t)(t-1)*B*D, 16, 0, Wd0Ih, Wd0Il, 32, 0, D };
        g1.op[1] = { featH + (size_t)bar*B*L, featL + (size_t)bar*B*L, 16, 0, Wd0Ih, Wd0Il, 32, 16, L };
        if (rs) g1.op[2] = { featH + (size_t)bar*B*L, featL + (size_t)bar*B*L, 16, 0, Wd0Hh, Wd0Hl, 16, 0, L };
        else    g1.op[2] = { hd1h[(t-1)&1], hd1l[(t-1)&1], 16, 0, Wd0Hh, Wd0Hl, 16, 0, L };
        g1.ci0 = bD0; g1.ld0 = 0; g1.mode = 1;
        g1.cin = rs ? featF + (size_t)bar*B*L : cd1; g1.cinLd = L;
        g1.cout = cd1; g1.coutLd = L;
        g1.hHi = hd1h[t&1]; g1.hLo = hd1l[t&1]; g1.hLdT = 16;
        return g1;
    };
    auto decG2 = [&](int t) {
        const int bar = t >> 4;
        const bool rs = (t & 15) == 0;
        MArgs g2{};
        g2.op[0] = { hd1h[t&1], hd1l[t&1], 16, 0, Wd1Ih, Wd1Il, 16, 0, L };
        if (rs) g2.op[1] = { featH + (size_t)bar*B*L, featL + (size_t)bar*B*L, 16, 0, Wd1Hh, Wd1Hl, 16, 0, L };
        else    g2.op[1] = { slabH + (size_t)(t-1)*B*L, slabL + (size_t)(t-1)*B*L, 16, 0, Wd1Hh, Wd1Hl, 16, 0, L };
        g2.ci0 = bD1; g2.ld0 = 0; g2.mode = 1;
        g2.cin = rs ? featF + (size_t)bar*B*L : cd2; g2.cinLd = L;
        g2.cout = cd2; g2.coutLd = L;
        g2.hHi = slabH + (size_t)t*B*L; g2.hLo = slabL + (size_t)t*B*L; g2.hLdT = 16;
        return g2;
    };
    {
        MArgs g1 = decG1(0);
        gemm_sk<4,0><<<dim3((4*L/64) * (B/32), 1, 1), 256, 0, stream>>>(g1, g1);
        for (int t = 0; t < T; ++t) {
            MArgs g2 = decG2(t);
            if (t + 1 < T) {
                MArgs n1 = decG1(t + 1);
                gemm_sk<4,0><<<dim3((4*L/64) * (B/32), 1, 2), 256, 0, stream>>>(g2, n1);
            } else {
                gemm_sk<4,0><<<dim3((4*L/64) * (B/32), 1, 1), 256, 0, stream>>>(g2, g2);
            }
        }
    }

    // ---------- logits (gemm_t 64x256 tile: 2x A-amp, proven 47 us) + softmax ----------
    {
        MArgs lg{};
        lg.op[0] = { slabH, slabL, 16, 0, WlogH, WlogL, 16, 0, L };
        lg.ci0 = blog; lg.ld0 = 0; lg.mode = 2;
        lg.out = prob_out; lg.outLd = D;
        gemm_t<5,2,2,4><<<dim3(D/256, T*B/64, 1), 512, 0, stream>>>(lg, lg);
    }
    softmax_all<<<B * T, 64, 0, stream>>>(prob_out, lab_out);
}